// Round 1
// baseline (184.041 us; speedup 1.0000x reference)
//
#include <hip/hip_runtime.h>
#include <hip/hip_bf16.h>

// ---------------------------------------------------------------------------
// TopologyBranch: persistence images (64x64, sigma=1) + 3-layer MLP
//   feats[b] = concat(PI(pairs_h0[b]), PI(pairs_h1[b]))   -> [256, 8192]
//   h  = relu(LN(feats @ W1 + b1))                        -> [256, 512]
//   h  = relu(LN(h @ W2 + b2))                            -> [256, 256]
//   out= h @ W3 + b3                                      -> [256, 128]
// Round 0: fp32 correctness-first baseline.
// ---------------------------------------------------------------------------

#define B_SZ 256
#define P0_N 1024
#define P1_N 512

// ---------------------------- Kernel A: persistence image ------------------
// One 256-thread block per (batch, hom). 512 blocks total.
__global__ __launch_bounds__(256) void pi_kernel(const float* __restrict__ p0,
                                                 const float* __restrict__ p1,
                                                 float* __restrict__ feats)
{
    const int task = blockIdx.x;          // 0..511
    const int b    = task >> 1;
    const int hom  = task & 1;
    const int P    = hom ? P1_N : P0_N;
    const float* pairs = hom ? (p1 + (size_t)b * P1_N * 2)
                             : (p0 + (size_t)b * P0_N * 2);
    const int t = threadIdx.x;

    __shared__ float sb[1024], sp[1024], sw[1024];      // 12 KB
    __shared__ float rmn[256], rmx[256], rpn[256], rpx[256]; // 4 KB
    __shared__ float kb[64][68], kp[64][68];            // ~34 KB (pad 68 -> conflict-free)

    // Phase 1: load points, per-thread masked min/max
    float bmin = 1e30f, bmax = -1e30f, pmin = 1e30f, pmax = -1e30f;
    for (int p = t; p < P; p += 256) {
        float birth = pairs[2 * p];
        float pers  = pairs[2 * p + 1] - birth;
        bool  valid = pers > 1e-6f;
        sb[p] = birth;
        sp[p] = pers;
        sw[p] = valid ? pers : 0.0f;
        if (valid) {
            bmin = fminf(bmin, birth); bmax = fmaxf(bmax, birth);
            pmin = fminf(pmin, pers);  pmax = fmaxf(pmax, pers);
        }
    }
    rmn[t] = bmin; rmx[t] = bmax; rpn[t] = pmin; rpx[t] = pmax;
    __syncthreads();
    for (int s = 128; s > 0; s >>= 1) {
        if (t < s) {
            rmn[t] = fminf(rmn[t], rmn[t + s]);
            rmx[t] = fmaxf(rmx[t], rmx[t + s]);
            rpn[t] = fminf(rpn[t], rpn[t + s]);
            rpx[t] = fmaxf(rpx[t], rpx[t + s]);
        }
        __syncthreads();
    }
    float bmn = rmn[0], bmx = rmx[0], pmn = rpn[0], pmx = rpx[0];
    // degenerate handling (also covers the "no valid points" case: w==0 -> img==0)
    if (bmx - bmn < 1e-6f) { bmn = 0.0f; bmx = 1.0f; }
    if (pmx - pmn < 1e-6f) { pmn = 0.0f; pmx = 1.0f; }
    const float binv = 1.0f / (bmx - bmn + 1e-8f);
    const float pinv = 1.0f / (pmx - pmn + 1e-8f);

    // Phase 2: normalize in place (each thread touches its own indices)
    for (int p = t; p < P; p += 256) {
        sb[p] = (sb[p] - bmn) * binv;
        sp[p] = (sp[p] - pmn) * pinv;
    }
    __syncthreads();

    // Phase 3: accumulate img[i][j] = sum_p w[p]*kb[p][i]*kp[p][j]
    // 4x4 register micro-tile per thread: 16x16 thread grid over 64x64 pixels.
    const int ti = t >> 4, tj = t & 15;
    const int i0 = ti * 4, j0 = tj * 4;
    float acc[4][4] = {};
    const int pl = t >> 2;   // point-in-chunk this thread evaluates kernels for
    const int cb = t & 3;    // interleaved column base (conflict-free writes)

    for (int c0 = 0; c0 < P; c0 += 64) {
        __syncthreads();   // protect kb/kp reuse (write-after-read)
        const float bnv = sb[c0 + pl];
        const float pnv = sp[c0 + pl];
        const float wv  = sw[c0 + pl];
        #pragma unroll
        for (int jj = 0; jj < 16; ++jj) {
            const int col = cb + jj * 4;
            const float g  = (float)col * (1.0f / 63.0f);
            const float db = g - bnv;
            const float dp = g - pnv;
            kb[pl][col] = wv * __expf(-db * db * 0.5f);  // w folded into kb
            kp[pl][col] = __expf(-dp * dp * 0.5f);
        }
        __syncthreads();
        #pragma unroll 4
        for (int p = 0; p < 64; ++p) {
            const float4 av = *(const float4*)&kb[p][i0];
            const float4 bv = *(const float4*)&kp[p][j0];
            acc[0][0] += av.x * bv.x; acc[0][1] += av.x * bv.y; acc[0][2] += av.x * bv.z; acc[0][3] += av.x * bv.w;
            acc[1][0] += av.y * bv.x; acc[1][1] += av.y * bv.y; acc[1][2] += av.y * bv.z; acc[1][3] += av.y * bv.w;
            acc[2][0] += av.z * bv.x; acc[2][1] += av.z * bv.y; acc[2][2] += av.z * bv.z; acc[2][3] += av.z * bv.w;
            acc[3][0] += av.w * bv.x; acc[3][1] += av.w * bv.y; acc[3][2] += av.w * bv.z; acc[3][3] += av.w * bv.w;
        }
    }

    // Phase 4: write image block into feats
    float* dst = feats + (size_t)b * 8192 + hom * 4096;
    #pragma unroll
    for (int ii = 0; ii < 4; ++ii) {
        float4 v = make_float4(acc[ii][0], acc[ii][1], acc[ii][2], acc[ii][3]);
        *(float4*)&dst[(i0 + ii) * 64 + j0] = v;
    }
}

// ---------------------------- Kernel B: GEMM1 (split-K) --------------------
// C = feats[256,8192] @ W1[8192,512], 64x64 tiles, K split 8 ways -> partials
__global__ __launch_bounds__(256) void gemm1_kernel(const float* __restrict__ A,
                                                    const float* __restrict__ W1,
                                                    float* __restrict__ part)
{
    const int mt = blockIdx.x;   // 0..3
    const int nt = blockIdx.y;   // 0..7
    const int ks = blockIdx.z;   // 0..7
    const int t  = threadIdx.x;

    __shared__ float Ast[16][68];   // A tile, transposed [k][m]
    __shared__ float Bs[16][68];    // B tile [k][n]

    const int mbase = mt * 64, nbase = nt * 64, kbase = ks * 1024;
    const int ti = t >> 4, tj = t & 15;
    const int la_m = t >> 2,  la_k = (t & 3) * 4;   // A: row, k-offset (float4)
    const int lb_k = t >> 4,  lb_n = (t & 15) * 4;  // B: k-row, n-offset (float4)

    float acc[4][4] = {};
    const float* Ap = A  + (size_t)(mbase + la_m) * 8192 + kbase + la_k;
    const float* Bp = W1 + (size_t)(kbase + lb_k) * 512  + nbase + lb_n;

    for (int k0 = 0; k0 < 1024; k0 += 16) {
        const float4 a4 = *(const float4*)(Ap + k0);
        const float4 b4 = *(const float4*)(Bp + (size_t)k0 * 512);
        Ast[la_k + 0][la_m] = a4.x;
        Ast[la_k + 1][la_m] = a4.y;
        Ast[la_k + 2][la_m] = a4.z;
        Ast[la_k + 3][la_m] = a4.w;
        *(float4*)&Bs[lb_k][lb_n] = b4;
        __syncthreads();
        #pragma unroll
        for (int kk = 0; kk < 16; ++kk) {
            const float4 av = *(const float4*)&Ast[kk][ti * 4];
            const float4 bv = *(const float4*)&Bs[kk][tj * 4];
            acc[0][0] += av.x * bv.x; acc[0][1] += av.x * bv.y; acc[0][2] += av.x * bv.z; acc[0][3] += av.x * bv.w;
            acc[1][0] += av.y * bv.x; acc[1][1] += av.y * bv.y; acc[1][2] += av.y * bv.z; acc[1][3] += av.y * bv.w;
            acc[2][0] += av.z * bv.x; acc[2][1] += av.z * bv.y; acc[2][2] += av.z * bv.z; acc[2][3] += av.z * bv.w;
            acc[3][0] += av.w * bv.x; acc[3][1] += av.w * bv.y; acc[3][2] += av.w * bv.z; acc[3][3] += av.w * bv.w;
        }
        __syncthreads();
    }

    float* dst = part + (size_t)ks * (256 * 512)
               + (size_t)(mbase + ti * 4) * 512 + nbase + tj * 4;
    #pragma unroll
    for (int ii = 0; ii < 4; ++ii) {
        *(float4*)&dst[(size_t)ii * 512] =
            make_float4(acc[ii][0], acc[ii][1], acc[ii][2], acc[ii][3]);
    }
}

// ---------------------------- Kernel C: fused tail -------------------------
// per row: reduce split-K partials + b1 -> LN -> relu -> @W2 + b2 -> LN ->
// relu -> @W3 + b3 -> out
__global__ __launch_bounds__(256) void tail_kernel(const float* __restrict__ part,
    const float* __restrict__ b1, const float* __restrict__ g1, const float* __restrict__ be1,
    const float* __restrict__ W2, const float* __restrict__ b2, const float* __restrict__ g2, const float* __restrict__ be2,
    const float* __restrict__ W3, const float* __restrict__ b3,
    float* __restrict__ out)
{
    const int row = blockIdx.x;
    const int t   = threadIdx.x;

    __shared__ float h1s[512];
    __shared__ float h2s[256];
    __shared__ float redA[256], redB[256];

    // reduce split-K partials (2 cols per thread) + bias
    float v0 = 0.0f, v1 = 0.0f;
    #pragma unroll
    for (int s = 0; s < 8; ++s) {
        v0 += part[(size_t)s * (256 * 512) + (size_t)row * 512 + t];
        v1 += part[(size_t)s * (256 * 512) + (size_t)row * 512 + t + 256];
    }
    v0 += b1[t];
    v1 += b1[t + 256];

    // LayerNorm over 512
    redA[t] = v0 + v1;
    redB[t] = v0 * v0 + v1 * v1;
    __syncthreads();
    for (int s = 128; s > 0; s >>= 1) {
        if (t < s) { redA[t] += redA[t + s]; redB[t] += redB[t + s]; }
        __syncthreads();
    }
    const float mu  = redA[0] * (1.0f / 512.0f);
    const float var = redB[0] * (1.0f / 512.0f) - mu * mu;
    const float rs  = rsqrtf(var + 1e-5f);
    h1s[t]       = fmaxf((v0 - mu) * rs * g1[t]       + be1[t],       0.0f);
    h1s[t + 256] = fmaxf((v1 - mu) * rs * g1[t + 256] + be1[t + 256], 0.0f);
    __syncthreads();

    // GEMM2: one output column per thread
    float a = 0.0f;
    #pragma unroll 4
    for (int k = 0; k < 512; ++k) a += h1s[k] * W2[(size_t)k * 256 + t];
    a += b2[t];

    // LayerNorm over 256
    __syncthreads();   // everyone done reading redA[0]/redB[0]
    redA[t] = a;
    redB[t] = a * a;
    __syncthreads();
    for (int s = 128; s > 0; s >>= 1) {
        if (t < s) { redA[t] += redA[t + s]; redB[t] += redB[t + s]; }
        __syncthreads();
    }
    const float mu2  = redA[0] * (1.0f / 256.0f);
    const float var2 = redB[0] * (1.0f / 256.0f) - mu2 * mu2;
    const float rs2  = rsqrtf(var2 + 1e-5f);
    h2s[t] = fmaxf((a - mu2) * rs2 * g2[t] + be2[t], 0.0f);
    __syncthreads();

    // GEMM3: 128 output columns (threads 0..127)
    if (t < 128) {
        float o = 0.0f;
        #pragma unroll 4
        for (int k = 0; k < 256; ++k) o += h2s[k] * W3[(size_t)k * 128 + t];
        out[(size_t)row * 128 + t] = o + b3[t];
    }
}

// ---------------------------------------------------------------------------
extern "C" void kernel_launch(void* const* d_in, const int* in_sizes, int n_in,
                              void* d_out, int out_size, void* d_ws, size_t ws_size,
                              hipStream_t stream)
{
    const float* p0  = (const float*)d_in[0];
    const float* p1  = (const float*)d_in[1];
    const float* W1  = (const float*)d_in[2];
    const float* b1  = (const float*)d_in[3];
    const float* g1  = (const float*)d_in[4];
    const float* be1 = (const float*)d_in[5];
    const float* W2  = (const float*)d_in[6];
    const float* b2  = (const float*)d_in[7];
    const float* g2  = (const float*)d_in[8];
    const float* be2 = (const float*)d_in[9];
    const float* W3  = (const float*)d_in[10];
    const float* b3  = (const float*)d_in[11];
    float* out = (float*)d_out;

    float* feats = (float*)d_ws;                       // 256*8192 floats (8 MB)
    float* part  = feats + (size_t)256 * 8192;         // 8*256*512 floats (4 MB)

    hipLaunchKernelGGL(pi_kernel,    dim3(512),     dim3(256), 0, stream, p0, p1, feats);
    hipLaunchKernelGGL(gemm1_kernel, dim3(4, 8, 8), dim3(256), 0, stream, feats, W1, part);
    hipLaunchKernelGGL(tail_kernel,  dim3(256),     dim3(256), 0, stream, part,
                       b1, g1, be1, W2, b2, g2, be2, W3, b3, out);
}

// Round 2
// 130.048 us; speedup vs baseline: 1.4152x; 1.4152x over previous
//
#include <hip/hip_runtime.h>
#include <hip/hip_bf16.h>
#include <hip/hip_fp16.h>

// ---------------------------------------------------------------------------
// TopologyBranch: persistence images (64x64, sigma=1) + 3-layer MLP
// Round 1: f16-dot2 8x8-microtile PI kernel; wide-parallel fused tail.
// ---------------------------------------------------------------------------

#define P0_N 1024
#define P1_N 512

typedef _Float16 h2 __attribute__((ext_vector_type(2)));

#if defined(__has_builtin)
#if __has_builtin(__builtin_amdgcn_fdot2)
#define HAVE_FDOT2 1
#endif
#endif

static __device__ __forceinline__ float fdot2_acc(h2 a, h2 b, float c) {
#ifdef HAVE_FDOT2
    return __builtin_amdgcn_fdot2(a, b, c, false);
#else
    return c + (float)a[0] * (float)b[0] + (float)a[1] * (float)b[1];
#endif
}

static __device__ __forceinline__ h2 bc_h2(int v) {
    return __builtin_bit_cast(h2, v);
}

// ---------------------------- Kernel A: persistence image ------------------
// One 256-thread block per (batch, hom). 512 blocks total.
// Phase 3: points chunked by 64; kernel values packed as f16 point-pairs in
// LDS; each wave owns 8 pairs (16 points); 8x8 pixel micro-tile per thread.
__global__ __launch_bounds__(256) void pi_kernel(const float* __restrict__ p0,
                                                 const float* __restrict__ p1,
                                                 float* __restrict__ feats)
{
    const int task = blockIdx.x;          // 0..511
    const int b    = task >> 1;
    const int hom  = task & 1;
    const int P    = hom ? P1_N : P0_N;
    const float* pairs = hom ? (p1 + (size_t)b * P1_N * 2)
                             : (p0 + (size_t)b * P0_N * 2);
    const int t = threadIdx.x;

    __shared__ float sb[1024], sp[1024], sw[1024];           // 12 KB
    __shared__ float rmn[256], rmx[256], rpn[256], rpx[256]; // 4 KB
    // kall[0] = kb (w folded), kall[1] = kp; [pair][col], pad 68 for banks.
    __shared__ __align__(16) __half2 kall[2][32][68];        // 17.4 KB

    // ---- Phase 1: load points, masked min/max ----
    float bmin = 1e30f, bmax = -1e30f, pmin = 1e30f, pmax = -1e30f;
    for (int p = t; p < P; p += 256) {
        float birth = pairs[2 * p];
        float pers  = pairs[2 * p + 1] - birth;
        bool  valid = pers > 1e-6f;
        sb[p] = birth;
        sp[p] = pers;
        sw[p] = valid ? pers : 0.0f;
        if (valid) {
            bmin = fminf(bmin, birth); bmax = fmaxf(bmax, birth);
            pmin = fminf(pmin, pers);  pmax = fmaxf(pmax, pers);
        }
    }
    rmn[t] = bmin; rmx[t] = bmax; rpn[t] = pmin; rpx[t] = pmax;
    __syncthreads();
    for (int s = 128; s > 0; s >>= 1) {
        if (t < s) {
            rmn[t] = fminf(rmn[t], rmn[t + s]);
            rmx[t] = fmaxf(rmx[t], rmx[t + s]);
            rpn[t] = fminf(rpn[t], rpn[t + s]);
            rpx[t] = fmaxf(rpx[t], rpx[t + s]);
        }
        __syncthreads();
    }
    float bmn = rmn[0], bmx = rmx[0], pmn = rpn[0], pmx = rpx[0];
    if (bmx - bmn < 1e-6f) { bmn = 0.0f; bmx = 1.0f; }
    if (pmx - pmn < 1e-6f) { pmn = 0.0f; pmx = 1.0f; }
    const float binv = 1.0f / (bmx - bmn + 1e-8f);
    const float pinv = 1.0f / (pmx - pmn + 1e-8f);

    // ---- Phase 2: normalize in place ----
    for (int p = t; p < P; p += 256) {
        sb[p] = (sb[p] - bmn) * binv;
        sp[p] = (sp[p] - pmn) * pinv;
    }
    __syncthreads();

    // ---- Phase 3: img[i][j] = sum_p w[p]*kb[p][i]*kp[p][j] ----
    const int slice = t >> 6;               // wave id 0..3 -> pair range
    const int lt = t & 63;
    const int ti = lt >> 3, tj = lt & 7;
    const int i0 = ti * 8, j0 = tj * 8;     // 8x8 pixel micro-tile
    const int gpp = t >> 3;                 // generation: pair id 0..31
    const int gcb = t & 7;                  // generation: col base

    float acc[8][8] = {};

    for (int c0 = 0; c0 < P; c0 += 64) {
        __syncthreads();   // protect kall reuse across chunks
        // generation: pair gpp = points (c0+2*gpp, c0+2*gpp+1)
        const float b0 = sb[c0 + 2 * gpp], b1 = sb[c0 + 2 * gpp + 1];
        const float q0 = sp[c0 + 2 * gpp], q1 = sp[c0 + 2 * gpp + 1];
        const float w0 = sw[c0 + 2 * gpp], w1 = sw[c0 + 2 * gpp + 1];
        #pragma unroll
        for (int jj = 0; jj < 8; ++jj) {
            const int col = gcb + jj * 8;
            const float g = (float)col * (1.0f / 63.0f);
            const float db0 = g - b0, db1 = g - b1;
            const float dq0 = g - q0, dq1 = g - q1;
            const float kb0 = w0 * __expf(-db0 * db0 * 0.5f);
            const float kb1 = w1 * __expf(-db1 * db1 * 0.5f);
            const float kp0 = __expf(-dq0 * dq0 * 0.5f);
            const float kp1 = __expf(-dq1 * dq1 * 0.5f);
            kall[0][gpp][col] = __floats2half2_rn(kb0, kb1);
            kall[1][gpp][col] = __floats2half2_rn(kp0, kp1);
        }
        __syncthreads();
        // consume: this wave handles pairs [slice*8, slice*8+8)
        #pragma unroll
        for (int it = 0; it < 8; ++it) {
            const int pp = slice * 8 + it;
            const int4 a0 = *(const int4*)&kall[0][pp][i0];
            const int4 a1 = *(const int4*)&kall[0][pp][i0 + 4];
            const int4 b0i = *(const int4*)&kall[1][pp][j0];
            const int4 b1i = *(const int4*)&kall[1][pp][j0 + 4];
            h2 A[8] = { bc_h2(a0.x), bc_h2(a0.y), bc_h2(a0.z), bc_h2(a0.w),
                        bc_h2(a1.x), bc_h2(a1.y), bc_h2(a1.z), bc_h2(a1.w) };
            h2 Bv[8] = { bc_h2(b0i.x), bc_h2(b0i.y), bc_h2(b0i.z), bc_h2(b0i.w),
                         bc_h2(b1i.x), bc_h2(b1i.y), bc_h2(b1i.z), bc_h2(b1i.w) };
            #pragma unroll
            for (int ii = 0; ii < 8; ++ii)
                #pragma unroll
                for (int jj = 0; jj < 8; ++jj)
                    acc[ii][jj] = fdot2_acc(A[ii], Bv[jj], acc[ii][jj]);
        }
    }

    // ---- Phase 4: cross-slice reduce via LDS (reuse kall), write out ----
    float* red = (float*)kall;    // 64*64 fp32 = 16 KB <= 17.4 KB
    __syncthreads();
    for (int s = 0; s < 4; ++s) {
        if (slice == s) {
            #pragma unroll
            for (int ii = 0; ii < 8; ++ii)
                #pragma unroll
                for (int jj = 0; jj < 8; ++jj) {
                    const int idx = (i0 + ii) * 64 + j0 + jj;
                    red[idx] = (s == 0) ? acc[ii][jj] : red[idx] + acc[ii][jj];
                }
        }
        __syncthreads();
    }
    float* dst = feats + (size_t)b * 8192 + hom * 4096;
    #pragma unroll
    for (int u = 0; u < 4; ++u) {
        const int idx = u * 1024 + t * 4;
        *(float4*)&dst[idx] = *(const float4*)&red[idx];
    }
}

// ---------------------------- Kernel B: GEMM1 (split-K) --------------------
// C = feats[256,8192] @ W1[8192,512], 64x64 tiles, K split 8 ways -> partials
__global__ __launch_bounds__(256) void gemm1_kernel(const float* __restrict__ A,
                                                    const float* __restrict__ W1,
                                                    float* __restrict__ part)
{
    const int mt = blockIdx.x;   // 0..3
    const int nt = blockIdx.y;   // 0..7
    const int ks = blockIdx.z;   // 0..7
    const int t  = threadIdx.x;

    __shared__ float Ast[16][68];   // A tile, transposed [k][m]
    __shared__ float Bs[16][68];    // B tile [k][n]

    const int mbase = mt * 64, nbase = nt * 64, kbase = ks * 1024;
    const int ti = t >> 4, tj = t & 15;
    const int la_m = t >> 2,  la_k = (t & 3) * 4;
    const int lb_k = t >> 4,  lb_n = (t & 15) * 4;

    float acc[4][4] = {};
    const float* Ap = A  + (size_t)(mbase + la_m) * 8192 + kbase + la_k;
    const float* Bp = W1 + (size_t)(kbase + lb_k) * 512  + nbase + lb_n;

    for (int k0 = 0; k0 < 1024; k0 += 16) {
        const float4 a4 = *(const float4*)(Ap + k0);
        const float4 b4 = *(const float4*)(Bp + (size_t)k0 * 512);
        Ast[la_k + 0][la_m] = a4.x;
        Ast[la_k + 1][la_m] = a4.y;
        Ast[la_k + 2][la_m] = a4.z;
        Ast[la_k + 3][la_m] = a4.w;
        *(float4*)&Bs[lb_k][lb_n] = b4;
        __syncthreads();
        #pragma unroll
        for (int kk = 0; kk < 16; ++kk) {
            const float4 av = *(const float4*)&Ast[kk][ti * 4];
            const float4 bv = *(const float4*)&Bs[kk][tj * 4];
            acc[0][0] += av.x * bv.x; acc[0][1] += av.x * bv.y; acc[0][2] += av.x * bv.z; acc[0][3] += av.x * bv.w;
            acc[1][0] += av.y * bv.x; acc[1][1] += av.y * bv.y; acc[1][2] += av.y * bv.z; acc[1][3] += av.y * bv.w;
            acc[2][0] += av.z * bv.x; acc[2][1] += av.z * bv.y; acc[2][2] += av.z * bv.z; acc[2][3] += av.z * bv.w;
            acc[3][0] += av.w * bv.x; acc[3][1] += av.w * bv.y; acc[3][2] += av.w * bv.z; acc[3][3] += av.w * bv.w;
        }
        __syncthreads();
    }

    float* dst = part + (size_t)ks * (256 * 512)
               + (size_t)(mbase + ti * 4) * 512 + nbase + tj * 4;
    #pragma unroll
    for (int ii = 0; ii < 4; ++ii) {
        *(float4*)&dst[(size_t)ii * 512] =
            make_float4(acc[ii][0], acc[ii][1], acc[ii][2], acc[ii][3]);
    }
}

// ---------------------------- Kernel C: fused tail -------------------------
// One block (1024 threads) per row. Split-K reduce + LN + relu + GEMM2 + LN +
// relu + GEMM3. All dot products K-split across threads for latency hiding.
__global__ __launch_bounds__(1024) void tail_kernel(const float* __restrict__ part,
    const float* __restrict__ b1, const float* __restrict__ g1, const float* __restrict__ be1,
    const float* __restrict__ W2, const float* __restrict__ b2, const float* __restrict__ g2, const float* __restrict__ be2,
    const float* __restrict__ W3, const float* __restrict__ b3,
    float* __restrict__ out)
{
    const int row  = blockIdx.x;
    const int t    = threadIdx.x;
    const int wid  = t >> 6, lane = t & 63;

    __shared__ float h1s[512];
    __shared__ float h2s[256];
    __shared__ float red[1024];
    __shared__ float wredA[16], wredB[16];

    // ---- Phase 1: reduce split-K partials (8 slabs) + bias ----
    const int col = t & 511, sb4 = (t >> 9) * 4;
    float v = 0.0f;
    #pragma unroll
    for (int s = 0; s < 4; ++s)
        v += part[(size_t)(sb4 + s) * (256 * 512) + (size_t)row * 512 + col];
    red[t] = v;
    __syncthreads();
    float x = 0.0f;
    if (t < 512) x = red[t] + red[t + 512] + b1[col];

    // ---- LN over 512 (values live on t<512) ----
    float s1 = (t < 512) ? x : 0.0f;
    float s2 = (t < 512) ? x * x : 0.0f;
    #pragma unroll
    for (int d = 32; d > 0; d >>= 1) {
        s1 += __shfl_xor(s1, d);
        s2 += __shfl_xor(s2, d);
    }
    if (lane == 0) { wredA[wid] = s1; wredB[wid] = s2; }
    __syncthreads();
    float mu = 0.0f, m2 = 0.0f;
    #pragma unroll
    for (int i = 0; i < 16; ++i) { mu += wredA[i]; m2 += wredB[i]; }
    mu *= (1.0f / 512.0f);
    m2  = m2 * (1.0f / 512.0f) - mu * mu;
    const float rs = rsqrtf(m2 + 1e-5f);
    if (t < 512) h1s[col] = fmaxf((x - mu) * rs * g1[col] + be1[col], 0.0f);
    __syncthreads();

    // ---- GEMM2: 256 cols x 4-way K-split (128 k each) ----
    const int col2 = t & 255, ks2 = t >> 8;
    float a = 0.0f;
    const float* w2p = W2 + (size_t)(ks2 * 128) * 256 + col2;
    const float* h1p = h1s + ks2 * 128;
    #pragma unroll 8
    for (int k = 0; k < 128; ++k) a += h1p[k] * w2p[(size_t)k * 256];
    red[t] = a;
    __syncthreads();
    float y = 0.0f;
    if (t < 256) y = red[t] + red[t + 256] + red[t + 512] + red[t + 768] + b2[t];

    // ---- LN over 256 (values live on t<256) ----
    s1 = (t < 256) ? y : 0.0f;
    s2 = (t < 256) ? y * y : 0.0f;
    #pragma unroll
    for (int d = 32; d > 0; d >>= 1) {
        s1 += __shfl_xor(s1, d);
        s2 += __shfl_xor(s2, d);
    }
    if (lane == 0) { wredA[wid] = s1; wredB[wid] = s2; }
    __syncthreads();
    mu = 0.0f; m2 = 0.0f;
    #pragma unroll
    for (int i = 0; i < 16; ++i) { mu += wredA[i]; m2 += wredB[i]; }
    mu *= (1.0f / 256.0f);
    m2  = m2 * (1.0f / 256.0f) - mu * mu;
    const float rs2 = rsqrtf(m2 + 1e-5f);
    if (t < 256) h2s[t] = fmaxf((y - mu) * rs2 * g2[t] + be2[t], 0.0f);
    __syncthreads();

    // ---- GEMM3: 128 cols x 8-way K-split (32 k each) ----
    const int col3 = t & 127, ks3 = t >> 7;
    float o = 0.0f;
    #pragma unroll 8
    for (int k = 0; k < 32; ++k)
        o += h2s[ks3 * 32 + k] * W3[(size_t)(ks3 * 32 + k) * 128 + col3];
    red[t] = o;
    __syncthreads();
    if (t < 128) {
        float oo = 0.0f;
        #pragma unroll
        for (int s = 0; s < 8; ++s) oo += red[t + s * 128];
        out[(size_t)row * 128 + t] = oo + b3[t];
    }
}

// ---------------------------------------------------------------------------
extern "C" void kernel_launch(void* const* d_in, const int* in_sizes, int n_in,
                              void* d_out, int out_size, void* d_ws, size_t ws_size,
                              hipStream_t stream)
{
    const float* p0  = (const float*)d_in[0];
    const float* p1  = (const float*)d_in[1];
    const float* W1  = (const float*)d_in[2];
    const float* b1  = (const float*)d_in[3];
    const float* g1  = (const float*)d_in[4];
    const float* be1 = (const float*)d_in[5];
    const float* W2  = (const float*)d_in[6];
    const float* b2  = (const float*)d_in[7];
    const float* g2  = (const float*)d_in[8];
    const float* be2 = (const float*)d_in[9];
    const float* W3  = (const float*)d_in[10];
    const float* b3  = (const float*)d_in[11];
    float* out = (float*)d_out;

    float* feats = (float*)d_ws;                       // 256*8192 floats (8 MB)
    float* part  = feats + (size_t)256 * 8192;         // 8*256*512 floats (4 MB)

    hipLaunchKernelGGL(pi_kernel,    dim3(512),     dim3(256),  0, stream, p0, p1, feats);
    hipLaunchKernelGGL(gemm1_kernel, dim3(4, 8, 8), dim3(256),  0, stream, feats, W1, part);
    hipLaunchKernelGGL(tail_kernel,  dim3(256),     dim3(1024), 0, stream, part,
                       b1, g1, be1, W2, b2, g2, be2, W3, b3, out);
}

// Round 3
// 89.200 us; speedup vs baseline: 2.0632x; 1.4579x over previous
//
#include <hip/hip_runtime.h>
#include <hip/hip_bf16.h>
#include <hip/hip_fp16.h>

// ---------------------------------------------------------------------------
// TopologyBranch: persistence images (64x64, sigma=1) + 3-layer MLP
// Round 2: GEMM1 -> f16 MFMA (feats emitted f16, W1 transposed+converted).
// ---------------------------------------------------------------------------

#define P0_N 1024
#define P1_N 512

typedef _Float16 h2 __attribute__((ext_vector_type(2)));
typedef _Float16 f16x8 __attribute__((ext_vector_type(8)));
typedef float f32x4 __attribute__((ext_vector_type(4)));

#if defined(__has_builtin)
#if __has_builtin(__builtin_amdgcn_fdot2)
#define HAVE_FDOT2 1
#endif
#endif

static __device__ __forceinline__ float fdot2_acc(h2 a, h2 b, float c) {
#ifdef HAVE_FDOT2
    return __builtin_amdgcn_fdot2(a, b, c, false);
#else
    return c + (float)a[0] * (float)b[0] + (float)a[1] * (float)b[1];
#endif
}

static __device__ __forceinline__ h2 bc_h2(int v) {
    return __builtin_bit_cast(h2, v);
}

// ---------------------------- Kernel A: persistence image ------------------
// One 256-thread block per (batch, hom). Output: feats in f16 [256][8192].
__global__ __launch_bounds__(256) void pi_kernel(const float* __restrict__ p0,
                                                 const float* __restrict__ p1,
                                                 _Float16* __restrict__ featsH)
{
    const int task = blockIdx.x;          // 0..511
    const int b    = task >> 1;
    const int hom  = task & 1;
    const int P    = hom ? P1_N : P0_N;
    const float* pairs = hom ? (p1 + (size_t)b * P1_N * 2)
                             : (p0 + (size_t)b * P0_N * 2);
    const int t = threadIdx.x;

    __shared__ float sb[1024], sp[1024], sw[1024];           // 12 KB
    __shared__ float rmn[256], rmx[256], rpn[256], rpx[256]; // 4 KB
    __shared__ __align__(16) __half2 kall[2][32][68];        // 17.4 KB

    // ---- Phase 1: load points, masked min/max ----
    float bmin = 1e30f, bmax = -1e30f, pmin = 1e30f, pmax = -1e30f;
    for (int p = t; p < P; p += 256) {
        float birth = pairs[2 * p];
        float pers  = pairs[2 * p + 1] - birth;
        bool  valid = pers > 1e-6f;
        sb[p] = birth;
        sp[p] = pers;
        sw[p] = valid ? pers : 0.0f;
        if (valid) {
            bmin = fminf(bmin, birth); bmax = fmaxf(bmax, birth);
            pmin = fminf(pmin, pers);  pmax = fmaxf(pmax, pers);
        }
    }
    rmn[t] = bmin; rmx[t] = bmax; rpn[t] = pmin; rpx[t] = pmax;
    __syncthreads();
    for (int s = 128; s > 0; s >>= 1) {
        if (t < s) {
            rmn[t] = fminf(rmn[t], rmn[t + s]);
            rmx[t] = fmaxf(rmx[t], rmx[t + s]);
            rpn[t] = fminf(rpn[t], rpn[t + s]);
            rpx[t] = fmaxf(rpx[t], rpx[t + s]);
        }
        __syncthreads();
    }
    float bmn = rmn[0], bmx = rmx[0], pmn = rpn[0], pmx = rpx[0];
    if (bmx - bmn < 1e-6f) { bmn = 0.0f; bmx = 1.0f; }
    if (pmx - pmn < 1e-6f) { pmn = 0.0f; pmx = 1.0f; }
    const float binv = 1.0f / (bmx - bmn + 1e-8f);
    const float pinv = 1.0f / (pmx - pmn + 1e-8f);

    // ---- Phase 2: normalize in place ----
    for (int p = t; p < P; p += 256) {
        sb[p] = (sb[p] - bmn) * binv;
        sp[p] = (sp[p] - pmn) * pinv;
    }
    __syncthreads();

    // ---- Phase 3: img[i][j] = sum_p w[p]*kb[p][i]*kp[p][j] ----
    const int slice = t >> 6;               // wave id 0..3 -> pair range
    const int lt = t & 63;
    const int ti = lt >> 3, tj = lt & 7;
    const int i0 = ti * 8, j0 = tj * 8;     // 8x8 pixel micro-tile
    const int gpp = t >> 3;                 // generation: pair id 0..31
    const int gcb = t & 7;                  // generation: col base

    float acc[8][8] = {};

    for (int c0 = 0; c0 < P; c0 += 64) {
        __syncthreads();   // protect kall reuse across chunks
        const float b0 = sb[c0 + 2 * gpp], b1 = sb[c0 + 2 * gpp + 1];
        const float q0 = sp[c0 + 2 * gpp], q1 = sp[c0 + 2 * gpp + 1];
        const float w0 = sw[c0 + 2 * gpp], w1 = sw[c0 + 2 * gpp + 1];
        #pragma unroll
        for (int jj = 0; jj < 8; ++jj) {
            const int col = gcb + jj * 8;
            const float g = (float)col * (1.0f / 63.0f);
            const float db0 = g - b0, db1 = g - b1;
            const float dq0 = g - q0, dq1 = g - q1;
            const float kb0 = w0 * __expf(-db0 * db0 * 0.5f);
            const float kb1 = w1 * __expf(-db1 * db1 * 0.5f);
            const float kp0 = __expf(-dq0 * dq0 * 0.5f);
            const float kp1 = __expf(-dq1 * dq1 * 0.5f);
            kall[0][gpp][col] = __floats2half2_rn(kb0, kb1);
            kall[1][gpp][col] = __floats2half2_rn(kp0, kp1);
        }
        __syncthreads();
        #pragma unroll
        for (int it = 0; it < 8; ++it) {
            const int pp = slice * 8 + it;
            const int4 a0 = *(const int4*)&kall[0][pp][i0];
            const int4 a1 = *(const int4*)&kall[0][pp][i0 + 4];
            const int4 b0i = *(const int4*)&kall[1][pp][j0];
            const int4 b1i = *(const int4*)&kall[1][pp][j0 + 4];
            h2 A[8] = { bc_h2(a0.x), bc_h2(a0.y), bc_h2(a0.z), bc_h2(a0.w),
                        bc_h2(a1.x), bc_h2(a1.y), bc_h2(a1.z), bc_h2(a1.w) };
            h2 Bv[8] = { bc_h2(b0i.x), bc_h2(b0i.y), bc_h2(b0i.z), bc_h2(b0i.w),
                         bc_h2(b1i.x), bc_h2(b1i.y), bc_h2(b1i.z), bc_h2(b1i.w) };
            #pragma unroll
            for (int ii = 0; ii < 8; ++ii)
                #pragma unroll
                for (int jj = 0; jj < 8; ++jj)
                    acc[ii][jj] = fdot2_acc(A[ii], Bv[jj], acc[ii][jj]);
        }
    }

    // ---- Phase 4: cross-slice reduce via LDS (reuse kall), write f16 ----
    float* red = (float*)kall;    // 64*64 fp32 = 16 KB
    __syncthreads();
    for (int s = 0; s < 4; ++s) {
        if (slice == s) {
            #pragma unroll
            for (int ii = 0; ii < 8; ++ii)
                #pragma unroll
                for (int jj = 0; jj < 8; ++jj) {
                    const int idx = (i0 + ii) * 64 + j0 + jj;
                    red[idx] = (s == 0) ? acc[ii][jj] : red[idx] + acc[ii][jj];
                }
        }
        __syncthreads();
    }
    _Float16* dst = featsH + (size_t)b * 8192 + hom * 4096;
    #pragma unroll
    for (int u = 0; u < 4; ++u) {
        const int idx = u * 1024 + t * 4;
        const float4 v = *(const float4*)&red[idx];
        _Float16 h4[4] = { (_Float16)v.x, (_Float16)v.y, (_Float16)v.z, (_Float16)v.w };
        *(uint2*)&dst[idx] = *(const uint2*)h4;
    }
}

// ---------------------------- Kernel B0: W1 transpose+convert --------------
// W1 [8192][512] f32 -> W1T [512][8192] f16. 64x64 tiles through LDS.
__global__ __launch_bounds__(256) void w1_transpose(const float* __restrict__ W1,
                                                    _Float16* __restrict__ W1T)
{
    const int kt = blockIdx.x;   // 0..127
    const int nt = blockIdx.y;   // 0..7
    const int t  = threadIdx.x;
    __shared__ _Float16 T[64][72];   // [n][k], pad 72

    {
        const int k = t >> 2, n0 = (t & 3) * 16;
        const float* src = W1 + (size_t)(kt * 64 + k) * 512 + nt * 64 + n0;
        const float4 v0 = *(const float4*)(src);
        const float4 v1 = *(const float4*)(src + 4);
        const float4 v2 = *(const float4*)(src + 8);
        const float4 v3 = *(const float4*)(src + 12);
        const float vals[16] = { v0.x, v0.y, v0.z, v0.w, v1.x, v1.y, v1.z, v1.w,
                                 v2.x, v2.y, v2.z, v2.w, v3.x, v3.y, v3.z, v3.w };
        #pragma unroll
        for (int j = 0; j < 16; ++j) T[n0 + j][k] = (_Float16)vals[j];
    }
    __syncthreads();
    {
        const int n = t >> 2, k0 = (t & 3) * 16;
        _Float16* dst = W1T + (size_t)(nt * 64 + n) * 8192 + kt * 64 + k0;
        *(uint4*)dst       = *(const uint4*)&T[n][k0];
        *(uint4*)(dst + 8) = *(const uint4*)&T[n][k0 + 8];
    }
}

// ---------------------------- Kernel B1: GEMM1 via MFMA --------------------
// C = feats[256,8192] @ W1[8192,512] with A,B^T in f16.
// 64x64 tiles, split-K 8 (slab 1024), 4 waves * (2x2) 16x16x32 frags.
__global__ __launch_bounds__(256) void gemm1_mfma(const _Float16* __restrict__ Ah,
                                                  const _Float16* __restrict__ BTh,
                                                  float* __restrict__ part)
{
    const int mt = blockIdx.x;   // 0..3
    const int nt = blockIdx.y;   // 0..7
    const int ks = blockIdx.z;   // 0..7
    const int t  = threadIdx.x;

    __shared__ _Float16 As[64][72];   // [m][k]
    __shared__ _Float16 Bs[64][72];   // [n][k]

    const int mbase = mt * 64, nbase = nt * 64, kbase = ks * 1024;
    const int lrow = t >> 2, lk0 = (t & 3) * 16;

    const _Float16* Ap = Ah  + (size_t)(mbase + lrow) * 8192 + kbase + lk0;
    const _Float16* Bp = BTh + (size_t)(nbase + lrow) * 8192 + kbase + lk0;

    const int w = t >> 6, lane = t & 63;
    const int wm = (w >> 1) * 32, wn = (w & 1) * 32;
    const int fr = lane & 15, fg = lane >> 4;

    f32x4 acc[2][2] = {};

    for (int k0 = 0; k0 < 1024; k0 += 64) {
        const uint4 a0 = *(const uint4*)(Ap + k0);
        const uint4 a1 = *(const uint4*)(Ap + k0 + 8);
        const uint4 b0 = *(const uint4*)(Bp + k0);
        const uint4 b1 = *(const uint4*)(Bp + k0 + 8);
        __syncthreads();                       // previous compute done
        *(uint4*)&As[lrow][lk0]     = a0;
        *(uint4*)&As[lrow][lk0 + 8] = a1;
        *(uint4*)&Bs[lrow][lk0]     = b0;
        *(uint4*)&Bs[lrow][lk0 + 8] = b1;
        __syncthreads();
        #pragma unroll
        for (int ks2 = 0; ks2 < 64; ks2 += 32) {
            f16x8 af[2], bf[2];
            af[0] = *(const f16x8*)&As[wm + fr][ks2 + fg * 8];
            af[1] = *(const f16x8*)&As[wm + 16 + fr][ks2 + fg * 8];
            bf[0] = *(const f16x8*)&Bs[wn + fr][ks2 + fg * 8];
            bf[1] = *(const f16x8*)&Bs[wn + 16 + fr][ks2 + fg * 8];
            #pragma unroll
            for (int i = 0; i < 2; ++i)
                #pragma unroll
                for (int j = 0; j < 2; ++j)
                    acc[i][j] = __builtin_amdgcn_mfma_f32_16x16x32_f16(
                        af[i], bf[j], acc[i][j], 0, 0, 0);
        }
    }

    // C/D layout: col = lane&15, row = (lane>>4)*4 + reg
    #pragma unroll
    for (int i = 0; i < 2; ++i)
        #pragma unroll
        for (int j = 0; j < 2; ++j) {
            const int r0 = mbase + wm + i * 16 + fg * 4;
            const int c  = nbase + wn + j * 16 + fr;
            float* dst = part + (size_t)ks * (256 * 512) + (size_t)r0 * 512 + c;
            #pragma unroll
            for (int r = 0; r < 4; ++r) dst[(size_t)r * 512] = acc[i][j][r];
        }
}

// ---------------------------- Kernel C: fused tail -------------------------
__global__ __launch_bounds__(1024) void tail_kernel(const float* __restrict__ part,
    const float* __restrict__ b1, const float* __restrict__ g1, const float* __restrict__ be1,
    const float* __restrict__ W2, const float* __restrict__ b2, const float* __restrict__ g2, const float* __restrict__ be2,
    const float* __restrict__ W3, const float* __restrict__ b3,
    float* __restrict__ out)
{
    const int row  = blockIdx.x;
    const int t    = threadIdx.x;
    const int wid  = t >> 6, lane = t & 63;

    __shared__ float h1s[512];
    __shared__ float h2s[256];
    __shared__ float red[1024];
    __shared__ float wredA[16], wredB[16];

    // ---- Phase 1: reduce split-K partials (8 slabs) + bias ----
    const int col = t & 511, sb4 = (t >> 9) * 4;
    float v = 0.0f;
    #pragma unroll
    for (int s = 0; s < 4; ++s)
        v += part[(size_t)(sb4 + s) * (256 * 512) + (size_t)row * 512 + col];
    red[t] = v;
    __syncthreads();
    float x = 0.0f;
    if (t < 512) x = red[t] + red[t + 512] + b1[col];

    // ---- LN over 512 ----
    float s1 = (t < 512) ? x : 0.0f;
    float s2 = (t < 512) ? x * x : 0.0f;
    #pragma unroll
    for (int d = 32; d > 0; d >>= 1) {
        s1 += __shfl_xor(s1, d);
        s2 += __shfl_xor(s2, d);
    }
    if (lane == 0) { wredA[wid] = s1; wredB[wid] = s2; }
    __syncthreads();
    float mu = 0.0f, m2 = 0.0f;
    #pragma unroll
    for (int i = 0; i < 16; ++i) { mu += wredA[i]; m2 += wredB[i]; }
    mu *= (1.0f / 512.0f);
    m2  = m2 * (1.0f / 512.0f) - mu * mu;
    const float rs = rsqrtf(m2 + 1e-5f);
    if (t < 512) h1s[col] = fmaxf((x - mu) * rs * g1[col] + be1[col], 0.0f);
    __syncthreads();

    // ---- GEMM2: 256 cols x 4-way K-split ----
    const int col2 = t & 255, ks2 = t >> 8;
    float a = 0.0f;
    const float* w2p = W2 + (size_t)(ks2 * 128) * 256 + col2;
    const float* h1p = h1s + ks2 * 128;
    #pragma unroll 8
    for (int k = 0; k < 128; ++k) a += h1p[k] * w2p[(size_t)k * 256];
    red[t] = a;
    __syncthreads();
    float y = 0.0f;
    if (t < 256) y = red[t] + red[t + 256] + red[t + 512] + red[t + 768] + b2[t];

    // ---- LN over 256 ----
    s1 = (t < 256) ? y : 0.0f;
    s2 = (t < 256) ? y * y : 0.0f;
    #pragma unroll
    for (int d = 32; d > 0; d >>= 1) {
        s1 += __shfl_xor(s1, d);
        s2 += __shfl_xor(s2, d);
    }
    if (lane == 0) { wredA[wid] = s1; wredB[wid] = s2; }
    __syncthreads();
    mu = 0.0f; m2 = 0.0f;
    #pragma unroll
    for (int i = 0; i < 16; ++i) { mu += wredA[i]; m2 += wredB[i]; }
    mu *= (1.0f / 256.0f);
    m2  = m2 * (1.0f / 256.0f) - mu * mu;
    const float rs2 = rsqrtf(m2 + 1e-5f);
    if (t < 256) h2s[t] = fmaxf((y - mu) * rs2 * g2[t] + be2[t], 0.0f);
    __syncthreads();

    // ---- GEMM3: 128 cols x 8-way K-split ----
    const int col3 = t & 127, ks3 = t >> 7;
    float o = 0.0f;
    #pragma unroll 8
    for (int k = 0; k < 32; ++k)
        o += h2s[ks3 * 32 + k] * W3[(size_t)(ks3 * 32 + k) * 128 + col3];
    red[t] = o;
    __syncthreads();
    if (t < 128) {
        float oo = 0.0f;
        #pragma unroll
        for (int s = 0; s < 8; ++s) oo += red[t + s * 128];
        out[(size_t)row * 128 + t] = oo + b3[t];
    }
}

// ---------------------------------------------------------------------------
extern "C" void kernel_launch(void* const* d_in, const int* in_sizes, int n_in,
                              void* d_out, int out_size, void* d_ws, size_t ws_size,
                              hipStream_t stream)
{
    const float* p0  = (const float*)d_in[0];
    const float* p1  = (const float*)d_in[1];
    const float* W1  = (const float*)d_in[2];
    const float* b1  = (const float*)d_in[3];
    const float* g1  = (const float*)d_in[4];
    const float* be1 = (const float*)d_in[5];
    const float* W2  = (const float*)d_in[6];
    const float* b2  = (const float*)d_in[7];
    const float* g2  = (const float*)d_in[8];
    const float* be2 = (const float*)d_in[9];
    const float* W3  = (const float*)d_in[10];
    const float* b3  = (const float*)d_in[11];
    float* out = (float*)d_out;

    // workspace: featsH 4MB | W1T 8MB | part 4MB  (16 MB total)
    _Float16* featsH = (_Float16*)d_ws;
    _Float16* w1t    = (_Float16*)((char*)d_ws + (4u << 20));
    float*    part   = (float*)((char*)d_ws + (12u << 20));

    hipLaunchKernelGGL(pi_kernel,    dim3(512),      dim3(256),  0, stream, p0, p1, featsH);
    hipLaunchKernelGGL(w1_transpose, dim3(128, 8),   dim3(256),  0, stream, W1, w1t);
    hipLaunchKernelGGL(gemm1_mfma,   dim3(4, 8, 8),  dim3(256),  0, stream, featsH, w1t, part);
    hipLaunchKernelGGL(tail_kernel,  dim3(256),      dim3(1024), 0, stream, part,
                       b1, g1, be1, W2, b2, g2, be2, W3, b3, out);
}

// Round 4
// 64.137 us; speedup vs baseline: 2.8695x; 1.3908x over previous
//
#include <hip/hip_runtime.h>
#include <hip/hip_bf16.h>
#include <hip/hip_fp16.h>

// ---------------------------------------------------------------------------
// TopologyBranch: persistence images (64x64, sigma=1) + 3-layer MLP
// Round 3: PI outer-product moved to f16 MFMA (gen kernel values transposed
//          in LDS, 4 waves x 2x2 16x16x32 frags); exp2 trick for Gaussians.
// ---------------------------------------------------------------------------

#define P0_N 1024
#define P1_N 512

typedef _Float16 h2 __attribute__((ext_vector_type(2)));
typedef _Float16 f16x8 __attribute__((ext_vector_type(8)));
typedef float f32x4 __attribute__((ext_vector_type(4)));

// sqrt(0.5 * log2(e)): exp(-0.5*d^2) == exp2(-(S*d)^2)
#define KSCALE 0.849321804f

// ---------------------------- Kernel A: persistence image ------------------
// One 256-thread block per (batch, hom). Output: feats in f16 [256][8192].
// img = (w o Kb)^T [64 x P] @ Kp [P x 64] via 16x16x32 f16 MFMA.
__global__ __launch_bounds__(256) void pi_kernel(const float* __restrict__ p0,
                                                 const float* __restrict__ p1,
                                                 _Float16* __restrict__ featsH)
{
    const int task = blockIdx.x;          // 0..511
    const int b    = task >> 1;
    const int hom  = task & 1;
    const int P    = hom ? P1_N : P0_N;
    const float* pairs = hom ? (p1 + (size_t)b * P1_N * 2)
                             : (p0 + (size_t)b * P0_N * 2);
    const int t = threadIdx.x;
    const int w = t >> 6, lane = t & 63;

    __shared__ float sb[1024], sp[1024], sw[1024];            // 12 KB
    __shared__ __align__(16) _Float16 kbT[64][72];            // [img_row][pt] 9 KB
    __shared__ __align__(16) _Float16 kpT[64][72];            // [img_col][pt] 9 KB
    __shared__ float wmn0[4], wmx0[4], wmn1[4], wmx1[4];

    // ---- Phase 1: load points, masked min/max (wave shuffle reduce) ----
    float bmin = 1e30f, bmax = -1e30f, pmin = 1e30f, pmax = -1e30f;
    for (int p = t; p < P; p += 256) {
        float birth = pairs[2 * p];
        float pers  = pairs[2 * p + 1] - birth;
        bool  valid = pers > 1e-6f;
        sb[p] = birth;
        sp[p] = pers;
        sw[p] = valid ? pers : 0.0f;
        if (valid) {
            bmin = fminf(bmin, birth); bmax = fmaxf(bmax, birth);
            pmin = fminf(pmin, pers);  pmax = fmaxf(pmax, pers);
        }
    }
    #pragma unroll
    for (int d = 32; d > 0; d >>= 1) {
        bmin = fminf(bmin, __shfl_xor(bmin, d));
        bmax = fmaxf(bmax, __shfl_xor(bmax, d));
        pmin = fminf(pmin, __shfl_xor(pmin, d));
        pmax = fmaxf(pmax, __shfl_xor(pmax, d));
    }
    if (lane == 0) { wmn0[w] = bmin; wmx0[w] = bmax; wmn1[w] = pmin; wmx1[w] = pmax; }
    __syncthreads();
    float bmn = fminf(fminf(wmn0[0], wmn0[1]), fminf(wmn0[2], wmn0[3]));
    float bmx = fmaxf(fmaxf(wmx0[0], wmx0[1]), fmaxf(wmx0[2], wmx0[3]));
    float pmn = fminf(fminf(wmn1[0], wmn1[1]), fminf(wmn1[2], wmn1[3]));
    float pmx = fmaxf(fmaxf(wmx1[0], wmx1[1]), fmaxf(wmx1[2], wmx1[3]));
    if (bmx - bmn < 1e-6f) { bmn = 0.0f; bmx = 1.0f; }
    if (pmx - pmn < 1e-6f) { pmn = 0.0f; pmx = 1.0f; }
    // fold the exp2 coordinate scale into the normalization
    const float binv = KSCALE / (bmx - bmn + 1e-8f);
    const float pinv = KSCALE / (pmx - pmn + 1e-8f);

    // ---- Phase 2: normalize (scaled) in place ----
    for (int p = t; p < P; p += 256) {
        sb[p] = (sb[p] - bmn) * binv;
        sp[p] = (sp[p] - pmn) * pinv;
    }

    // ---- Phase 3: chunks of 64 points; gen transposed f16, consume MFMA ----
    const int pr = t >> 3;        // pair 0..31 (points 2pr, 2pr+1 of chunk)
    const int cb = t & 7;         // col base for generation
    const int wm = (w >> 1) * 32, wn = (w & 1) * 32;   // wave quadrant
    const int fr = lane & 15, fg = lane >> 4;

    f32x4 acc[2][2] = {};

    for (int c0 = 0; c0 < P; c0 += 64) {
        __syncthreads();   // prev consume done / phase-2 visible
        const float b0 = sb[c0 + 2 * pr], b1 = sb[c0 + 2 * pr + 1];
        const float q0 = sp[c0 + 2 * pr], q1 = sp[c0 + 2 * pr + 1];
        const float w0 = sw[c0 + 2 * pr], w1 = sw[c0 + 2 * pr + 1];
        #pragma unroll
        for (int jj = 0; jj < 8; ++jj) {
            const int c = cb + jj * 8;
            const float g = (float)c * (KSCALE / 63.0f);
            const float d0 = g - b0, d1 = g - b1;
            const float e0 = g - q0, e1 = g - q1;
            const float kb0 = w0 * exp2f(-(d0 * d0));
            const float kb1 = w1 * exp2f(-(d1 * d1));
            const float kp0 = exp2f(-(e0 * e0));
            const float kp1 = exp2f(-(e1 * e1));
            h2 vb; vb[0] = (_Float16)kb0; vb[1] = (_Float16)kb1;
            h2 vp; vp[0] = (_Float16)kp0; vp[1] = (_Float16)kp1;
            *(h2*)&kbT[c][2 * pr] = vb;
            *(h2*)&kpT[c][2 * pr] = vp;
        }
        __syncthreads();
        #pragma unroll
        for (int ks2 = 0; ks2 < 64; ks2 += 32) {
            f16x8 af[2], bf[2];
            af[0] = *(const f16x8*)&kbT[wm + fr][ks2 + fg * 8];
            af[1] = *(const f16x8*)&kbT[wm + 16 + fr][ks2 + fg * 8];
            bf[0] = *(const f16x8*)&kpT[wn + fr][ks2 + fg * 8];
            bf[1] = *(const f16x8*)&kpT[wn + 16 + fr][ks2 + fg * 8];
            #pragma unroll
            for (int i = 0; i < 2; ++i)
                #pragma unroll
                for (int j = 0; j < 2; ++j)
                    acc[i][j] = __builtin_amdgcn_mfma_f32_16x16x32_f16(
                        af[i], bf[j], acc[i][j], 0, 0, 0);
        }
    }

    // ---- Phase 4: write quadrant directly (C/D: col=lane&15, row=fg*4+r) ----
    _Float16* dst = featsH + (size_t)b * 8192 + hom * 4096;
    #pragma unroll
    for (int i = 0; i < 2; ++i)
        #pragma unroll
        for (int j = 0; j < 2; ++j) {
            const int r0 = wm + i * 16 + fg * 4;
            const int c  = wn + j * 16 + fr;
            #pragma unroll
            for (int r = 0; r < 4; ++r)
                dst[(size_t)(r0 + r) * 64 + c] = (_Float16)acc[i][j][r];
        }
}

// ---------------------------- Kernel B0: W1 transpose+convert --------------
// W1 [8192][512] f32 -> W1T [512][8192] f16. 64x64 tiles through LDS.
__global__ __launch_bounds__(256) void w1_transpose(const float* __restrict__ W1,
                                                    _Float16* __restrict__ W1T)
{
    const int kt = blockIdx.x;   // 0..127
    const int nt = blockIdx.y;   // 0..7
    const int t  = threadIdx.x;
    __shared__ _Float16 T[64][72];   // [n][k], pad 72

    {
        const int k = t >> 2, n0 = (t & 3) * 16;
        const float* src = W1 + (size_t)(kt * 64 + k) * 512 + nt * 64 + n0;
        const float4 v0 = *(const float4*)(src);
        const float4 v1 = *(const float4*)(src + 4);
        const float4 v2 = *(const float4*)(src + 8);
        const float4 v3 = *(const float4*)(src + 12);
        const float vals[16] = { v0.x, v0.y, v0.z, v0.w, v1.x, v1.y, v1.z, v1.w,
                                 v2.x, v2.y, v2.z, v2.w, v3.x, v3.y, v3.z, v3.w };
        #pragma unroll
        for (int j = 0; j < 16; ++j) T[n0 + j][k] = (_Float16)vals[j];
    }
    __syncthreads();
    {
        const int n = t >> 2, k0 = (t & 3) * 16;
        _Float16* dst = W1T + (size_t)(nt * 64 + n) * 8192 + kt * 64 + k0;
        *(uint4*)dst       = *(const uint4*)&T[n][k0];
        *(uint4*)(dst + 8) = *(const uint4*)&T[n][k0 + 8];
    }
}

// ---------------------------- Kernel B1: GEMM1 via MFMA --------------------
// C = feats[256,8192] @ W1[8192,512] with A,B^T in f16.
// 64x64 tiles, split-K 8 (slab 1024), 4 waves * (2x2) 16x16x32 frags.
__global__ __launch_bounds__(256) void gemm1_mfma(const _Float16* __restrict__ Ah,
                                                  const _Float16* __restrict__ BTh,
                                                  float* __restrict__ part)
{
    const int mt = blockIdx.x;   // 0..3
    const int nt = blockIdx.y;   // 0..7
    const int ks = blockIdx.z;   // 0..7
    const int t  = threadIdx.x;

    __shared__ _Float16 As[64][72];   // [m][k]
    __shared__ _Float16 Bs[64][72];   // [n][k]

    const int mbase = mt * 64, nbase = nt * 64, kbase = ks * 1024;
    const int lrow = t >> 2, lk0 = (t & 3) * 16;

    const _Float16* Ap = Ah  + (size_t)(mbase + lrow) * 8192 + kbase + lk0;
    const _Float16* Bp = BTh + (size_t)(nbase + lrow) * 8192 + kbase + lk0;

    const int w = t >> 6, lane = t & 63;
    const int wm = (w >> 1) * 32, wn = (w & 1) * 32;
    const int fr = lane & 15, fg = lane >> 4;

    f32x4 acc[2][2] = {};

    for (int k0 = 0; k0 < 1024; k0 += 64) {
        const uint4 a0 = *(const uint4*)(Ap + k0);
        const uint4 a1 = *(const uint4*)(Ap + k0 + 8);
        const uint4 b0 = *(const uint4*)(Bp + k0);
        const uint4 b1 = *(const uint4*)(Bp + k0 + 8);
        __syncthreads();                       // previous compute done
        *(uint4*)&As[lrow][lk0]     = a0;
        *(uint4*)&As[lrow][lk0 + 8] = a1;
        *(uint4*)&Bs[lrow][lk0]     = b0;
        *(uint4*)&Bs[lrow][lk0 + 8] = b1;
        __syncthreads();
        #pragma unroll
        for (int ks2 = 0; ks2 < 64; ks2 += 32) {
            f16x8 af[2], bf[2];
            af[0] = *(const f16x8*)&As[wm + fr][ks2 + fg * 8];
            af[1] = *(const f16x8*)&As[wm + 16 + fr][ks2 + fg * 8];
            bf[0] = *(const f16x8*)&Bs[wn + fr][ks2 + fg * 8];
            bf[1] = *(const f16x8*)&Bs[wn + 16 + fr][ks2 + fg * 8];
            #pragma unroll
            for (int i = 0; i < 2; ++i)
                #pragma unroll
                for (int j = 0; j < 2; ++j)
                    acc[i][j] = __builtin_amdgcn_mfma_f32_16x16x32_f16(
                        af[i], bf[j], acc[i][j], 0, 0, 0);
        }
    }

    // C/D layout: col = lane&15, row = (lane>>4)*4 + reg
    #pragma unroll
    for (int i = 0; i < 2; ++i)
        #pragma unroll
        for (int j = 0; j < 2; ++j) {
            const int r0 = mbase + wm + i * 16 + fg * 4;
            const int c  = nbase + wn + j * 16 + fr;
            float* dst = part + (size_t)ks * (256 * 512) + (size_t)r0 * 512 + c;
            #pragma unroll
            for (int r = 0; r < 4; ++r) dst[(size_t)r * 512] = acc[i][j][r];
        }
}

// ---------------------------- Kernel C: fused tail -------------------------
__global__ __launch_bounds__(1024) void tail_kernel(const float* __restrict__ part,
    const float* __restrict__ b1, const float* __restrict__ g1, const float* __restrict__ be1,
    const float* __restrict__ W2, const float* __restrict__ b2, const float* __restrict__ g2, const float* __restrict__ be2,
    const float* __restrict__ W3, const float* __restrict__ b3,
    float* __restrict__ out)
{
    const int row  = blockIdx.x;
    const int t    = threadIdx.x;
    const int wid  = t >> 6, lane = t & 63;

    __shared__ float h1s[512];
    __shared__ float h2s[256];
    __shared__ float red[1024];
    __shared__ float wredA[16], wredB[16];

    // ---- Phase 1: reduce split-K partials (8 slabs) + bias ----
    const int col = t & 511, sb4 = (t >> 9) * 4;
    float v = 0.0f;
    #pragma unroll
    for (int s = 0; s < 4; ++s)
        v += part[(size_t)(sb4 + s) * (256 * 512) + (size_t)row * 512 + col];
    red[t] = v;
    __syncthreads();
    float x = 0.0f;
    if (t < 512) x = red[t] + red[t + 512] + b1[col];

    // ---- LN over 512 ----
    float s1 = (t < 512) ? x : 0.0f;
    float s2 = (t < 512) ? x * x : 0.0f;
    #pragma unroll
    for (int d = 32; d > 0; d >>= 1) {
        s1 += __shfl_xor(s1, d);
        s2 += __shfl_xor(s2, d);
    }
    if (lane == 0) { wredA[wid] = s1; wredB[wid] = s2; }
    __syncthreads();
    float mu = 0.0f, m2 = 0.0f;
    #pragma unroll
    for (int i = 0; i < 16; ++i) { mu += wredA[i]; m2 += wredB[i]; }
    mu *= (1.0f / 512.0f);
    m2  = m2 * (1.0f / 512.0f) - mu * mu;
    const float rs = rsqrtf(m2 + 1e-5f);
    if (t < 512) h1s[col] = fmaxf((x - mu) * rs * g1[col] + be1[col], 0.0f);
    __syncthreads();

    // ---- GEMM2: 256 cols x 4-way K-split ----
    const int col2 = t & 255, ks2 = t >> 8;
    float a = 0.0f;
    const float* w2p = W2 + (size_t)(ks2 * 128) * 256 + col2;
    const float* h1p = h1s + ks2 * 128;
    #pragma unroll 8
    for (int k = 0; k < 128; ++k) a += h1p[k] * w2p[(size_t)k * 256];
    red[t] = a;
    __syncthreads();
    float y = 0.0f;
    if (t < 256) y = red[t] + red[t + 256] + red[t + 512] + red[t + 768] + b2[t];

    // ---- LN over 256 ----
    s1 = (t < 256) ? y : 0.0f;
    s2 = (t < 256) ? y * y : 0.0f;
    #pragma unroll
    for (int d = 32; d > 0; d >>= 1) {
        s1 += __shfl_xor(s1, d);
        s2 += __shfl_xor(s2, d);
    }
    if (lane == 0) { wredA[wid] = s1; wredB[wid] = s2; }
    __syncthreads();
    mu = 0.0f; m2 = 0.0f;
    #pragma unroll
    for (int i = 0; i < 16; ++i) { mu += wredA[i]; m2 += wredB[i]; }
    mu *= (1.0f / 256.0f);
    m2  = m2 * (1.0f / 256.0f) - mu * mu;
    const float rs2 = rsqrtf(m2 + 1e-5f);
    if (t < 256) h2s[t] = fmaxf((y - mu) * rs2 * g2[t] + be2[t], 0.0f);
    __syncthreads();

    // ---- GEMM3: 128 cols x 8-way K-split ----
    const int col3 = t & 127, ks3 = t >> 7;
    float o = 0.0f;
    #pragma unroll 8
    for (int k = 0; k < 32; ++k)
        o += h2s[ks3 * 32 + k] * W3[(size_t)(ks3 * 32 + k) * 128 + col3];
    red[t] = o;
    __syncthreads();
    if (t < 128) {
        float oo = 0.0f;
        #pragma unroll
        for (int s = 0; s < 8; ++s) oo += red[t + s * 128];
        out[(size_t)row * 128 + t] = oo + b3[t];
    }
}

// ---------------------------------------------------------------------------
extern "C" void kernel_launch(void* const* d_in, const int* in_sizes, int n_in,
                              void* d_out, int out_size, void* d_ws, size_t ws_size,
                              hipStream_t stream)
{
    const float* p0  = (const float*)d_in[0];
    const float* p1  = (const float*)d_in[1];
    const float* W1  = (const float*)d_in[2];
    const float* b1  = (const float*)d_in[3];
    const float* g1  = (const float*)d_in[4];
    const float* be1 = (const float*)d_in[5];
    const float* W2  = (const float*)d_in[6];
    const float* b2  = (const float*)d_in[7];
    const float* g2  = (const float*)d_in[8];
    const float* be2 = (const float*)d_in[9];
    const float* W3  = (const float*)d_in[10];
    const float* b3  = (const float*)d_in[11];
    float* out = (float*)d_out;

    // workspace: featsH 4MB | W1T 8MB | part 4MB  (16 MB total)
    _Float16* featsH = (_Float16*)d_ws;
    _Float16* w1t    = (_Float16*)((char*)d_ws + (4u << 20));
    float*    part   = (float*)((char*)d_ws + (12u << 20));

    hipLaunchKernelGGL(pi_kernel,    dim3(512),      dim3(256),  0, stream, p0, p1, featsH);
    hipLaunchKernelGGL(w1_transpose, dim3(128, 8),   dim3(256),  0, stream, W1, w1t);
    hipLaunchKernelGGL(gemm1_mfma,   dim3(4, 8, 8),  dim3(256),  0, stream, featsH, w1t, part);
    hipLaunchKernelGGL(tail_kernel,  dim3(256),      dim3(1024), 0, stream, part,
                       b1, g1, be1, W2, b2, g2, be2, W3, b3, out);
}

// Round 5
// 53.424 us; speedup vs baseline: 3.4449x; 1.2005x over previous
//
#include <hip/hip_runtime.h>
#include <hip/hip_bf16.h>
#include <hip/hip_fp16.h>

// ---------------------------------------------------------------------------
// TopologyBranch: persistence images (64x64, sigma=1) + 3-layer MLP
// Round 5: raw v_exp_f32 via builtin in pi; w1_transpose fused into gemm1
//          (f32 W1 read + in-LDS transpose + reg prefetch); tail GEMM2
//          vectorized (float4 W2, 16-way K-split).
// ---------------------------------------------------------------------------

#define P0_N 1024
#define P1_N 512

typedef _Float16 h2 __attribute__((ext_vector_type(2)));
typedef _Float16 f16x8 __attribute__((ext_vector_type(8)));
typedef float f32x4 __attribute__((ext_vector_type(4)));

// sqrt(0.5 * log2(e)): exp(-0.5*d^2) == exp2(-(S*d)^2)
#define KSCALE 0.849321804f

static __device__ __forceinline__ float fast_exp2(float x) {
#if defined(__has_builtin)
#if __has_builtin(__builtin_amdgcn_exp2f)
    return __builtin_amdgcn_exp2f(x);   // raw v_exp_f32
#else
    return exp2f(x);
#endif
#else
    return exp2f(x);
#endif
}

// ---------------------------- Kernel A: persistence image ------------------
// One 256-thread block per (batch, hom). Output: feats in f16 [256][8192].
// img = (w o Kb)^T [64 x P] @ Kp [P x 64] via 16x16x32 f16 MFMA.
__global__ __launch_bounds__(256) void pi_kernel(const float* __restrict__ p0,
                                                 const float* __restrict__ p1,
                                                 _Float16* __restrict__ featsH)
{
    const int task = blockIdx.x;          // 0..511
    const int b    = task >> 1;
    const int hom  = task & 1;
    const int P    = hom ? P1_N : P0_N;
    const float* pairs = hom ? (p1 + (size_t)b * P1_N * 2)
                             : (p0 + (size_t)b * P0_N * 2);
    const int t = threadIdx.x;
    const int w = t >> 6, lane = t & 63;

    __shared__ float sb[1024], sp[1024], sw[1024];            // 12 KB
    __shared__ __align__(16) _Float16 kbT[64][72];            // [img_row][pt] 9 KB
    __shared__ __align__(16) _Float16 kpT[64][72];            // [img_col][pt] 9 KB
    __shared__ float wmn0[4], wmx0[4], wmn1[4], wmx1[4];

    // ---- Phase 1: load points, masked min/max (wave shuffle reduce) ----
    float bmin = 1e30f, bmax = -1e30f, pmin = 1e30f, pmax = -1e30f;
    for (int p = t; p < P; p += 256) {
        float birth = pairs[2 * p];
        float pers  = pairs[2 * p + 1] - birth;
        bool  valid = pers > 1e-6f;
        sb[p] = birth;
        sp[p] = pers;
        sw[p] = valid ? pers : 0.0f;
        if (valid) {
            bmin = fminf(bmin, birth); bmax = fmaxf(bmax, birth);
            pmin = fminf(pmin, pers);  pmax = fmaxf(pmax, pers);
        }
    }
    #pragma unroll
    for (int d = 32; d > 0; d >>= 1) {
        bmin = fminf(bmin, __shfl_xor(bmin, d));
        bmax = fmaxf(bmax, __shfl_xor(bmax, d));
        pmin = fminf(pmin, __shfl_xor(pmin, d));
        pmax = fmaxf(pmax, __shfl_xor(pmax, d));
    }
    if (lane == 0) { wmn0[w] = bmin; wmx0[w] = bmax; wmn1[w] = pmin; wmx1[w] = pmax; }
    __syncthreads();
    float bmn = fminf(fminf(wmn0[0], wmn0[1]), fminf(wmn0[2], wmn0[3]));
    float bmx = fmaxf(fmaxf(wmx0[0], wmx0[1]), fmaxf(wmx0[2], wmx0[3]));
    float pmn = fminf(fminf(wmn1[0], wmn1[1]), fminf(wmn1[2], wmn1[3]));
    float pmx = fmaxf(fmaxf(wmx1[0], wmx1[1]), fmaxf(wmx1[2], wmx1[3]));
    if (bmx - bmn < 1e-6f) { bmn = 0.0f; bmx = 1.0f; }
    if (pmx - pmn < 1e-6f) { pmn = 0.0f; pmx = 1.0f; }
    // fold the exp2 coordinate scale into the normalization
    const float binv = KSCALE / (bmx - bmn + 1e-8f);
    const float pinv = KSCALE / (pmx - pmn + 1e-8f);

    // ---- Phase 2: normalize (scaled) in place ----
    for (int p = t; p < P; p += 256) {
        sb[p] = (sb[p] - bmn) * binv;
        sp[p] = (sp[p] - pmn) * pinv;
    }

    // ---- Phase 3: chunks of 64 points; gen transposed f16, consume MFMA ----
    const int pr = t >> 3;        // pair 0..31 (points 2pr, 2pr+1 of chunk)
    const int cb = t & 7;         // col base for generation
    const int wm = (w >> 1) * 32, wn = (w & 1) * 32;   // wave quadrant
    const int fr = lane & 15, fg = lane >> 4;

    f32x4 acc[2][2] = {};

    for (int c0 = 0; c0 < P; c0 += 64) {
        __syncthreads();   // prev consume done / phase-2 visible
        const float b0 = sb[c0 + 2 * pr], b1 = sb[c0 + 2 * pr + 1];
        const float q0 = sp[c0 + 2 * pr], q1 = sp[c0 + 2 * pr + 1];
        const float w0 = sw[c0 + 2 * pr], w1 = sw[c0 + 2 * pr + 1];
        #pragma unroll
        for (int jj = 0; jj < 8; ++jj) {
            const int c = cb + jj * 8;
            const float g = (float)c * (KSCALE / 63.0f);
            const float d0 = g - b0, d1 = g - b1;
            const float e0 = g - q0, e1 = g - q1;
            const float kb0 = w0 * fast_exp2(-(d0 * d0));
            const float kb1 = w1 * fast_exp2(-(d1 * d1));
            const float kp0 = fast_exp2(-(e0 * e0));
            const float kp1 = fast_exp2(-(e1 * e1));
            h2 vb; vb[0] = (_Float16)kb0; vb[1] = (_Float16)kb1;
            h2 vp; vp[0] = (_Float16)kp0; vp[1] = (_Float16)kp1;
            *(h2*)&kbT[c][2 * pr] = vb;
            *(h2*)&kpT[c][2 * pr] = vp;
        }
        __syncthreads();
        #pragma unroll
        for (int ks2 = 0; ks2 < 64; ks2 += 32) {
            f16x8 af[2], bf[2];
            af[0] = *(const f16x8*)&kbT[wm + fr][ks2 + fg * 8];
            af[1] = *(const f16x8*)&kbT[wm + 16 + fr][ks2 + fg * 8];
            bf[0] = *(const f16x8*)&kpT[wn + fr][ks2 + fg * 8];
            bf[1] = *(const f16x8*)&kpT[wn + 16 + fr][ks2 + fg * 8];
            #pragma unroll
            for (int i = 0; i < 2; ++i)
                #pragma unroll
                for (int j = 0; j < 2; ++j)
                    acc[i][j] = __builtin_amdgcn_mfma_f32_16x16x32_f16(
                        af[i], bf[j], acc[i][j], 0, 0, 0);
        }
    }

    // ---- Phase 4: write quadrant directly (C/D: col=lane&15, row=fg*4+r) ----
    _Float16* dst = featsH + (size_t)b * 8192 + hom * 4096;
    #pragma unroll
    for (int i = 0; i < 2; ++i)
        #pragma unroll
        for (int j = 0; j < 2; ++j) {
            const int r0 = wm + i * 16 + fg * 4;
            const int c  = wn + j * 16 + fr;
            #pragma unroll
            for (int r = 0; r < 4; ++r)
                dst[(size_t)(r0 + r) * 64 + c] = (_Float16)acc[i][j][r];
        }
}

// ---------------------------- Kernel B: GEMM1 via MFMA ---------------------
// C = feats[256,8192] @ W1[8192,512]; A f16, W1 read as f32 and transposed
// into LDS (f16) on the fly. 64x64 tiles, split-K 8, reg prefetch 1-deep.
__global__ __launch_bounds__(256) void gemm1_mfma(const _Float16* __restrict__ Ah,
                                                  const float* __restrict__ W1,
                                                  float* __restrict__ part)
{
    const int mt = blockIdx.x;   // 0..3
    const int nt = blockIdx.y;   // 0..7
    const int ks = blockIdx.z;   // 0..7
    const int t  = threadIdx.x;

    __shared__ _Float16 As[64][72];   // [m][k]
    __shared__ _Float16 Bs[64][72];   // [n][k]

    const int mbase = mt * 64, nbase = nt * 64, kbase = ks * 1024;
    const int lrow = t >> 2, lk0 = (t & 3) * 16;   // A staging
    const int kr   = t >> 2, c0  = (t & 3) * 16;   // W1 staging (row kr, 16 cols)

    const _Float16* Ap = Ah + (size_t)(mbase + lrow) * 8192 + kbase + lk0;
    const float*    Wp = W1 + (size_t)(kbase + kr) * 512 + nbase + c0;

    const int w = t >> 6, lane = t & 63;
    const int wm = (w >> 1) * 32, wn = (w & 1) * 32;
    const int fr = lane & 15, fg = lane >> 4;

    f32x4 acc[2][2] = {};

    // prefetch iter 0
    uint4  pa0 = *(const uint4*)(Ap);
    uint4  pa1 = *(const uint4*)(Ap + 8);
    float4 pw0 = *(const float4*)(Wp);
    float4 pw1 = *(const float4*)(Wp + 4);
    float4 pw2 = *(const float4*)(Wp + 8);
    float4 pw3 = *(const float4*)(Wp + 12);

    for (int k0 = 0; k0 < 1024; k0 += 64) {
        __syncthreads();                       // previous MFMA reads done
        *(uint4*)&As[lrow][lk0]     = pa0;
        *(uint4*)&As[lrow][lk0 + 8] = pa1;
        {
            const float wv[16] = { pw0.x, pw0.y, pw0.z, pw0.w,
                                   pw1.x, pw1.y, pw1.z, pw1.w,
                                   pw2.x, pw2.y, pw2.z, pw2.w,
                                   pw3.x, pw3.y, pw3.z, pw3.w };
            #pragma unroll
            for (int j = 0; j < 16; ++j) Bs[c0 + j][kr] = (_Float16)wv[j];
        }
        __syncthreads();
        if (k0 + 64 < 1024) {                  // prefetch next iter
            pa0 = *(const uint4*)(Ap + k0 + 64);
            pa1 = *(const uint4*)(Ap + k0 + 72);
            const float* wn_ = Wp + (size_t)(k0 + 64) * 512;
            pw0 = *(const float4*)(wn_);
            pw1 = *(const float4*)(wn_ + 4);
            pw2 = *(const float4*)(wn_ + 8);
            pw3 = *(const float4*)(wn_ + 12);
        }
        #pragma unroll
        for (int ks2 = 0; ks2 < 64; ks2 += 32) {
            f16x8 af[2], bf[2];
            af[0] = *(const f16x8*)&As[wm + fr][ks2 + fg * 8];
            af[1] = *(const f16x8*)&As[wm + 16 + fr][ks2 + fg * 8];
            bf[0] = *(const f16x8*)&Bs[wn + fr][ks2 + fg * 8];
            bf[1] = *(const f16x8*)&Bs[wn + 16 + fr][ks2 + fg * 8];
            #pragma unroll
            for (int i = 0; i < 2; ++i)
                #pragma unroll
                for (int j = 0; j < 2; ++j)
                    acc[i][j] = __builtin_amdgcn_mfma_f32_16x16x32_f16(
                        af[i], bf[j], acc[i][j], 0, 0, 0);
        }
    }

    // C/D layout: col = lane&15, row = (lane>>4)*4 + reg
    #pragma unroll
    for (int i = 0; i < 2; ++i)
        #pragma unroll
        for (int j = 0; j < 2; ++j) {
            const int r0 = mbase + wm + i * 16 + fg * 4;
            const int c  = nbase + wn + j * 16 + fr;
            float* dst = part + (size_t)ks * (256 * 512) + (size_t)r0 * 512 + c;
            #pragma unroll
            for (int r = 0; r < 4; ++r) dst[(size_t)r * 512] = acc[i][j][r];
        }
}

// ---------------------------- Kernel C: fused tail -------------------------
__global__ __launch_bounds__(1024) void tail_kernel(const float* __restrict__ part,
    const float* __restrict__ b1, const float* __restrict__ g1, const float* __restrict__ be1,
    const float* __restrict__ W2, const float* __restrict__ b2, const float* __restrict__ g2, const float* __restrict__ be2,
    const float* __restrict__ W3, const float* __restrict__ b3,
    float* __restrict__ out)
{
    const int row  = blockIdx.x;
    const int t    = threadIdx.x;
    const int wid  = t >> 6, lane = t & 63;

    __shared__ float h1s[512];
    __shared__ float h2s[256];
    __shared__ float red[1024];
    __shared__ __align__(16) float red4[1024][4];   // 16 KB
    __shared__ float wredA[16], wredB[16];

    // ---- Phase 1: reduce split-K partials (8 slabs) + bias ----
    const int col = t & 511, sb4 = (t >> 9) * 4;
    float v = 0.0f;
    #pragma unroll
    for (int s = 0; s < 4; ++s)
        v += part[(size_t)(sb4 + s) * (256 * 512) + (size_t)row * 512 + col];
    red[t] = v;
    __syncthreads();
    float x = 0.0f;
    if (t < 512) x = red[t] + red[t + 512] + b1[col];

    // ---- LN over 512 ----
    float s1 = (t < 512) ? x : 0.0f;
    float s2 = (t < 512) ? x * x : 0.0f;
    #pragma unroll
    for (int d = 32; d > 0; d >>= 1) {
        s1 += __shfl_xor(s1, d);
        s2 += __shfl_xor(s2, d);
    }
    if (lane == 0) { wredA[wid] = s1; wredB[wid] = s2; }
    __syncthreads();
    float mu = 0.0f, m2 = 0.0f;
    #pragma unroll
    for (int i = 0; i < 16; ++i) { mu += wredA[i]; m2 += wredB[i]; }
    mu *= (1.0f / 512.0f);
    m2  = m2 * (1.0f / 512.0f) - mu * mu;
    const float rs = rsqrtf(m2 + 1e-5f);
    if (t < 512) h1s[col] = fmaxf((x - mu) * rs * g1[col] + be1[col], 0.0f);
    __syncthreads();

    // ---- GEMM2: 64 col-groups (float4) x 16-way K-split (32 k each) ----
    const int cg2 = t & 63, ksl = t >> 6;
    {
        float4 a4 = make_float4(0.0f, 0.0f, 0.0f, 0.0f);
        const float* w2p = W2 + (size_t)(ksl * 32) * 256 + cg2 * 4;
        const float* h1p = h1s + ksl * 32;
        #pragma unroll 8
        for (int k = 0; k < 32; ++k) {
            const float4 wv = *(const float4*)(w2p + (size_t)k * 256);
            const float hv = h1p[k];
            a4.x += hv * wv.x; a4.y += hv * wv.y;
            a4.z += hv * wv.z; a4.w += hv * wv.w;
        }
        *(float4*)red4[t] = a4;
    }
    __syncthreads();
    float y = 0.0f;
    if (t < 256) {
        const float* r4f = (const float*)red4;
        const int base = (t >> 2) * 4 + (t & 3);
        #pragma unroll
        for (int s = 0; s < 16; ++s) y += r4f[s * 256 + base];
        y += b2[t];
    }

    // ---- LN over 256 ----
    s1 = (t < 256) ? y : 0.0f;
    s2 = (t < 256) ? y * y : 0.0f;
    #pragma unroll
    for (int d = 32; d > 0; d >>= 1) {
        s1 += __shfl_xor(s1, d);
        s2 += __shfl_xor(s2, d);
    }
    if (lane == 0) { wredA[wid] = s1; wredB[wid] = s2; }
    __syncthreads();
    mu = 0.0f; m2 = 0.0f;
    #pragma unroll
    for (int i = 0; i < 16; ++i) { mu += wredA[i]; m2 += wredB[i]; }
    mu *= (1.0f / 256.0f);
    m2  = m2 * (1.0f / 256.0f) - mu * mu;
    const float rs2 = rsqrtf(m2 + 1e-5f);
    if (t < 256) h2s[t] = fmaxf((y - mu) * rs2 * g2[t] + be2[t], 0.0f);
    __syncthreads();

    // ---- GEMM3: 128 cols x 8-way K-split ----
    const int col3 = t & 127, ks3 = t >> 7;
    float o = 0.0f;
    #pragma unroll 8
    for (int k = 0; k < 32; ++k)
        o += h2s[ks3 * 32 + k] * W3[(size_t)(ks3 * 32 + k) * 128 + col3];
    red[t] = o;
    __syncthreads();
    if (t < 128) {
        float oo = 0.0f;
        #pragma unroll
        for (int s = 0; s < 8; ++s) oo += red[t + s * 128];
        out[(size_t)row * 128 + t] = oo + b3[t];
    }
}

// ---------------------------------------------------------------------------
extern "C" void kernel_launch(void* const* d_in, const int* in_sizes, int n_in,
                              void* d_out, int out_size, void* d_ws, size_t ws_size,
                              hipStream_t stream)
{
    const float* p0  = (const float*)d_in[0];
    const float* p1  = (const float*)d_in[1];
    const float* W1  = (const float*)d_in[2];
    const float* b1  = (const float*)d_in[3];
    const float* g1  = (const float*)d_in[4];
    const float* be1 = (const float*)d_in[5];
    const float* W2  = (const float*)d_in[6];
    const float* b2  = (const float*)d_in[7];
    const float* g2  = (const float*)d_in[8];
    const float* be2 = (const float*)d_in[9];
    const float* W3  = (const float*)d_in[10];
    const float* b3  = (const float*)d_in[11];
    float* out = (float*)d_out;

    // workspace: featsH 4MB | part 4MB
    _Float16* featsH = (_Float16*)d_ws;
    float*    part   = (float*)((char*)d_ws + (4u << 20));

    hipLaunchKernelGGL(pi_kernel,    dim3(512),      dim3(256),  0, stream, p0, p1, featsH);
    hipLaunchKernelGGL(gemm1_mfma,   dim3(4, 8, 8),  dim3(256),  0, stream, featsH, W1, part);
    hipLaunchKernelGGL(tail_kernel,  dim3(256),      dim3(1024), 0, stream, part,
                       b1, g1, be1, W2, b2, g2, be2, W3, b3, out);
}

// Round 6
// 42.213 us; speedup vs baseline: 4.3598x; 1.2656x over previous
//
#include <hip/hip_runtime.h>
#include <hip/hip_bf16.h>
#include <hip/hip_fp16.h>

// ---------------------------------------------------------------------------
// TopologyBranch: persistence images (64x64, sigma=1) + 3-layer MLP
// Round 6: pi = valid-point compaction + geometric-recurrence Gaussian gen
//          (2 exps + 2 muls/col instead of exp per col); gemm1 split-K 16.
// ---------------------------------------------------------------------------

#define P0_N 1024
#define P1_N 512

typedef _Float16 h2 __attribute__((ext_vector_type(2)));
typedef _Float16 f16x8 __attribute__((ext_vector_type(8)));
typedef float f32x4 __attribute__((ext_vector_type(4)));

// sqrt(0.5 * log2(e)): exp(-0.5*d^2) == exp2(-(S*d)^2)
#define KSCALE 0.849321804f
#define DG (KSCALE / 63.0f)          // scaled grid step

static __device__ __forceinline__ float fast_exp2(float x) {
#if defined(__has_builtin)
#if __has_builtin(__builtin_amdgcn_exp2f)
    return __builtin_amdgcn_exp2f(x);   // raw v_exp_f32
#else
    return exp2f(x);
#endif
#else
    return exp2f(x);
#endif
}

// ---------------------------- Kernel A: persistence image ------------------
// One 256-thread block per (batch, hom). Output: feats in f16 [256][8192].
// img = (w o Kb)^T [64 x Pv] @ Kp [Pv x 64] via 16x16x32 f16 MFMA over
// compacted valid points only.
__global__ __launch_bounds__(256) void pi_kernel(const float* __restrict__ p0,
                                                 const float* __restrict__ p1,
                                                 _Float16* __restrict__ featsH)
{
    const int task = blockIdx.x;          // 0..511
    const int b    = task >> 1;
    const int hom  = task & 1;
    const int P    = hom ? P1_N : P0_N;
    const float* pairs = hom ? (p1 + (size_t)b * P1_N * 2)
                             : (p0 + (size_t)b * P0_N * 2);
    const int t = threadIdx.x;
    const int w = t >> 6, lane = t & 63;

    __shared__ float cbs[1024], cps[1024], cws[1024];         // compacted, 12 KB
    __shared__ __align__(16) _Float16 kbT[64][72];            // [img_row][pt] 9 KB
    __shared__ __align__(16) _Float16 kpT[64][72];            // [img_col][pt] 9 KB
    __shared__ float wmn0[4], wmx0[4], wmn1[4], wmx1[4];
    __shared__ unsigned gcnt[16];

    // ---- Phase 1: load points (<=4 slots/thread), masked min/max ----
    float bv_[4], pv_[4];
    bool  val[4];
    float bmin = 1e30f, bmax = -1e30f, pmin = 1e30f, pmax = -1e30f;
    #pragma unroll
    for (int s = 0; s < 4; ++s) {
        const int p = t + s * 256;
        val[s] = false; bv_[s] = 0.0f; pv_[s] = 0.0f;
        if (p < P) {
            const float2 pr = ((const float2*)pairs)[p];
            const float birth = pr.x;
            const float pers  = pr.y - pr.x;
            bv_[s] = birth; pv_[s] = pers;
            val[s] = pers > 1e-6f;
            if (val[s]) {
                bmin = fminf(bmin, birth); bmax = fmaxf(bmax, birth);
                pmin = fminf(pmin, pers);  pmax = fmaxf(pmax, pers);
            }
        }
    }
    #pragma unroll
    for (int d = 32; d > 0; d >>= 1) {
        bmin = fminf(bmin, __shfl_xor(bmin, d));
        bmax = fmaxf(bmax, __shfl_xor(bmax, d));
        pmin = fminf(pmin, __shfl_xor(pmin, d));
        pmax = fmaxf(pmax, __shfl_xor(pmax, d));
    }
    // ballots for compaction (all lanes get the mask)
    unsigned long long msk[4];
    #pragma unroll
    for (int s = 0; s < 4; ++s) msk[s] = __ballot(val[s]);
    if (lane == 0) {
        wmn0[w] = bmin; wmx0[w] = bmax; wmn1[w] = pmin; wmx1[w] = pmax;
        #pragma unroll
        for (int s = 0; s < 4; ++s) gcnt[w * 4 + s] = (unsigned)__popcll(msk[s]);
    }
    __syncthreads();
    float bmn = fminf(fminf(wmn0[0], wmn0[1]), fminf(wmn0[2], wmn0[3]));
    float bmx = fmaxf(fmaxf(wmx0[0], wmx0[1]), fmaxf(wmx0[2], wmx0[3]));
    float pmn = fminf(fminf(wmn1[0], wmn1[1]), fminf(wmn1[2], wmn1[3]));
    float pmx = fmaxf(fmaxf(wmx1[0], wmx1[1]), fmaxf(wmx1[2], wmx1[3]));
    if (bmx - bmn < 1e-6f) { bmn = 0.0f; bmx = 1.0f; }
    if (pmx - pmn < 1e-6f) { pmn = 0.0f; pmx = 1.0f; }
    const float binv = KSCALE / (bmx - bmn + 1e-8f);   // exp2 scale folded in
    const float pinv = KSCALE / (pmx - pmn + 1e-8f);

    // prefix over the 16 group counts (every thread, branch-free-ish)
    unsigned gb[4] = {0, 0, 0, 0};
    unsigned run = 0;
    #pragma unroll
    for (int g = 0; g < 16; ++g) {
        #pragma unroll
        for (int s = 0; s < 4; ++s)
            if (g == w * 4 + s) gb[s] = run;
        run += gcnt[g];
    }
    const int nv = (int)run;
    const int nchunks = (nv + 63) >> 6;

    // ---- Phase 2: scatter compacted normalized coords + weights ----
    const unsigned long long below = (1ull << lane) - 1ull;
    #pragma unroll
    for (int s = 0; s < 4; ++s) {
        if (val[s]) {
            const unsigned pos = gb[s] + (unsigned)__popcll(msk[s] & below);
            cbs[pos] = (bv_[s] - bmn) * binv;
            cps[pos] = (pv_[s] - pmn) * pinv;
            cws[pos] = pv_[s];
        }
    }
    // zero-pad to chunk multiple
    for (int i = nv + t; i < nchunks * 64; i += 256) {
        cbs[i] = 0.0f; cps[i] = 0.0f; cws[i] = 0.0f;
    }

    // ---- Phase 3: per chunk: recurrence gen (f16, transposed) + MFMA ----
    // gen mapping: pp = lane&31 (point pair), surf = lane>=32, quarter q = w
    const int pp   = lane & 31;
    const int surf = lane >> 5;
    const int c0   = w * 16;
    const float Gq = (float)c0 * DG;
    const float rho = fast_exp2(-2.0f * DG * DG);
    const float c1  = -DG * DG * (float)(2 * c0 + 1);
    const float* Xarr = surf ? cps : cbs;
    _Float16* surfT = surf ? &kpT[0][0] : &kbT[0][0];

    // consume mapping (per wave quadrant)
    const int wm = (w >> 1) * 32, wn = (w & 1) * 32;
    const int fr = lane & 15, fg = lane >> 4;

    f32x4 acc[2][2] = {};

    for (int c = 0; c < nchunks; ++c) {
        const int base = c * 64;
        __syncthreads();   // prev consume done / compaction visible
        // --- gen: 2 points x 16 cols, geometric recurrence ---
        const float X0 = Xarr[base + 2 * pp];
        const float X1 = Xarr[base + 2 * pp + 1];
        float W0 = 1.0f, W1 = 1.0f;
        if (!surf) { W0 = cws[base + 2 * pp]; W1 = cws[base + 2 * pp + 1]; }
        const float d0 = Gq - X0, d1 = Gq - X1;
        float v0 = W0 * fast_exp2(-(d0 * d0));
        float v1 = W1 * fast_exp2(-(d1 * d1));
        float r0 = fast_exp2(c1 + 2.0f * DG * X0);
        float r1 = fast_exp2(c1 + 2.0f * DG * X1);
        #pragma unroll
        for (int j = 0; j < 16; ++j) {
            h2 hv; hv[0] = (_Float16)v0; hv[1] = (_Float16)v1;
            *(h2*)&surfT[(c0 + j) * 72 + 2 * pp] = hv;
            v0 *= r0; r0 *= rho;
            v1 *= r1; r1 *= rho;
        }
        __syncthreads();
        // --- consume: 2x2 16x16x32 MFMA over the 64-point chunk ---
        #pragma unroll
        for (int ks2 = 0; ks2 < 64; ks2 += 32) {
            f16x8 af[2], bf[2];
            af[0] = *(const f16x8*)&kbT[wm + fr][ks2 + fg * 8];
            af[1] = *(const f16x8*)&kbT[wm + 16 + fr][ks2 + fg * 8];
            bf[0] = *(const f16x8*)&kpT[wn + fr][ks2 + fg * 8];
            bf[1] = *(const f16x8*)&kpT[wn + 16 + fr][ks2 + fg * 8];
            #pragma unroll
            for (int i = 0; i < 2; ++i)
                #pragma unroll
                for (int j = 0; j < 2; ++j)
                    acc[i][j] = __builtin_amdgcn_mfma_f32_16x16x32_f16(
                        af[i], bf[j], acc[i][j], 0, 0, 0);
        }
    }

    // ---- Phase 4: write quadrant (C/D: col=lane&15, row=fg*4+r) ----
    _Float16* dst = featsH + (size_t)b * 8192 + hom * 4096;
    #pragma unroll
    for (int i = 0; i < 2; ++i)
        #pragma unroll
        for (int j = 0; j < 2; ++j) {
            const int r0_ = wm + i * 16 + fg * 4;
            const int cc  = wn + j * 16 + fr;
            #pragma unroll
            for (int r = 0; r < 4; ++r)
                dst[(size_t)(r0_ + r) * 64 + cc] = (_Float16)acc[i][j][r];
        }
}

// ---------------------------- Kernel B: GEMM1 via MFMA ---------------------
// C = feats[256,8192] @ W1[8192,512]; A f16, W1 read as f32 and transposed
// into LDS (f16) on the fly. 64x64 tiles, split-K 16, reg prefetch 1-deep.
__global__ __launch_bounds__(256) void gemm1_mfma(const _Float16* __restrict__ Ah,
                                                  const float* __restrict__ W1,
                                                  float* __restrict__ part)
{
    const int mt = blockIdx.x;   // 0..3
    const int nt = blockIdx.y;   // 0..7
    const int ks = blockIdx.z;   // 0..15
    const int t  = threadIdx.x;

    __shared__ _Float16 As[64][72];   // [m][k]
    __shared__ _Float16 Bs[64][72];   // [n][k]

    const int mbase = mt * 64, nbase = nt * 64, kbase = ks * 512;
    const int lrow = t >> 2, lk0 = (t & 3) * 16;   // A staging
    const int kr   = t >> 2, c0  = (t & 3) * 16;   // W1 staging (row kr, 16 cols)

    const _Float16* Ap = Ah + (size_t)(mbase + lrow) * 8192 + kbase + lk0;
    const float*    Wp = W1 + (size_t)(kbase + kr) * 512 + nbase + c0;

    const int w = t >> 6, lane = t & 63;
    const int wm = (w >> 1) * 32, wn = (w & 1) * 32;
    const int fr = lane & 15, fg = lane >> 4;

    f32x4 acc[2][2] = {};

    // prefetch iter 0
    uint4  pa0 = *(const uint4*)(Ap);
    uint4  pa1 = *(const uint4*)(Ap + 8);
    float4 pw0 = *(const float4*)(Wp);
    float4 pw1 = *(const float4*)(Wp + 4);
    float4 pw2 = *(const float4*)(Wp + 8);
    float4 pw3 = *(const float4*)(Wp + 12);

    for (int k0 = 0; k0 < 512; k0 += 64) {
        __syncthreads();                       // previous MFMA reads done
        *(uint4*)&As[lrow][lk0]     = pa0;
        *(uint4*)&As[lrow][lk0 + 8] = pa1;
        {
            const float wv[16] = { pw0.x, pw0.y, pw0.z, pw0.w,
                                   pw1.x, pw1.y, pw1.z, pw1.w,
                                   pw2.x, pw2.y, pw2.z, pw2.w,
                                   pw3.x, pw3.y, pw3.z, pw3.w };
            #pragma unroll
            for (int j = 0; j < 16; ++j) Bs[c0 + j][kr] = (_Float16)wv[j];
        }
        __syncthreads();
        if (k0 + 64 < 512) {                   // prefetch next iter
            pa0 = *(const uint4*)(Ap + k0 + 64);
            pa1 = *(const uint4*)(Ap + k0 + 72);
            const float* wn_ = Wp + (size_t)(k0 + 64) * 512;
            pw0 = *(const float4*)(wn_);
            pw1 = *(const float4*)(wn_ + 4);
            pw2 = *(const float4*)(wn_ + 8);
            pw3 = *(const float4*)(wn_ + 12);
        }
        #pragma unroll
        for (int ks2 = 0; ks2 < 64; ks2 += 32) {
            f16x8 af[2], bf[2];
            af[0] = *(const f16x8*)&As[wm + fr][ks2 + fg * 8];
            af[1] = *(const f16x8*)&As[wm + 16 + fr][ks2 + fg * 8];
            bf[0] = *(const f16x8*)&Bs[wn + fr][ks2 + fg * 8];
            bf[1] = *(const f16x8*)&Bs[wn + 16 + fr][ks2 + fg * 8];
            #pragma unroll
            for (int i = 0; i < 2; ++i)
                #pragma unroll
                for (int j = 0; j < 2; ++j)
                    acc[i][j] = __builtin_amdgcn_mfma_f32_16x16x32_f16(
                        af[i], bf[j], acc[i][j], 0, 0, 0);
        }
    }

    // C/D layout: col = lane&15, row = (lane>>4)*4 + reg
    #pragma unroll
    for (int i = 0; i < 2; ++i)
        #pragma unroll
        for (int j = 0; j < 2; ++j) {
            const int r0 = mbase + wm + i * 16 + fg * 4;
            const int c  = nbase + wn + j * 16 + fr;
            float* dst = part + (size_t)ks * (256 * 512) + (size_t)r0 * 512 + c;
            #pragma unroll
            for (int r = 0; r < 4; ++r) dst[(size_t)r * 512] = acc[i][j][r];
        }
}

// ---------------------------- Kernel C: fused tail -------------------------
__global__ __launch_bounds__(1024) void tail_kernel(const float* __restrict__ part,
    const float* __restrict__ b1, const float* __restrict__ g1, const float* __restrict__ be1,
    const float* __restrict__ W2, const float* __restrict__ b2, const float* __restrict__ g2, const float* __restrict__ be2,
    const float* __restrict__ W3, const float* __restrict__ b3,
    float* __restrict__ out)
{
    const int row  = blockIdx.x;
    const int t    = threadIdx.x;
    const int wid  = t >> 6, lane = t & 63;

    __shared__ float h1s[512];
    __shared__ float h2s[256];
    __shared__ float red[1024];
    __shared__ __align__(16) float red4[1024][4];   // 16 KB
    __shared__ float wredA[16], wredB[16];

    // ---- Phase 1: reduce split-K partials (16 slabs) + bias ----
    const int col = t & 511, sb8 = (t >> 9) * 8;
    float v = 0.0f;
    #pragma unroll
    for (int s = 0; s < 8; ++s)
        v += part[(size_t)(sb8 + s) * (256 * 512) + (size_t)row * 512 + col];
    red[t] = v;
    __syncthreads();
    float x = 0.0f;
    if (t < 512) x = red[t] + red[t + 512] + b1[col];

    // ---- LN over 512 ----
    float s1 = (t < 512) ? x : 0.0f;
    float s2 = (t < 512) ? x * x : 0.0f;
    #pragma unroll
    for (int d = 32; d > 0; d >>= 1) {
        s1 += __shfl_xor(s1, d);
        s2 += __shfl_xor(s2, d);
    }
    if (lane == 0) { wredA[wid] = s1; wredB[wid] = s2; }
    __syncthreads();
    float mu = 0.0f, m2 = 0.0f;
    #pragma unroll
    for (int i = 0; i < 16; ++i) { mu += wredA[i]; m2 += wredB[i]; }
    mu *= (1.0f / 512.0f);
    m2  = m2 * (1.0f / 512.0f) - mu * mu;
    const float rs = rsqrtf(m2 + 1e-5f);
    if (t < 512) h1s[col] = fmaxf((x - mu) * rs * g1[col] + be1[col], 0.0f);
    __syncthreads();

    // ---- GEMM2: 64 col-groups (float4) x 16-way K-split (32 k each) ----
    const int cg2 = t & 63, ksl = t >> 6;
    {
        float4 a4 = make_float4(0.0f, 0.0f, 0.0f, 0.0f);
        const float* w2p = W2 + (size_t)(ksl * 32) * 256 + cg2 * 4;
        const float* h1p = h1s + ksl * 32;
        #pragma unroll 8
        for (int k = 0; k < 32; ++k) {
            const float4 wv = *(const float4*)(w2p + (size_t)k * 256);
            const float hv = h1p[k];
            a4.x += hv * wv.x; a4.y += hv * wv.y;
            a4.z += hv * wv.z; a4.w += hv * wv.w;
        }
        *(float4*)red4[t] = a4;
    }
    __syncthreads();
    float y = 0.0f;
    if (t < 256) {
        const float* r4f = (const float*)red4;
        const int base = (t >> 2) * 4 + (t & 3);
        #pragma unroll
        for (int s = 0; s < 16; ++s) y += r4f[s * 256 + base];
        y += b2[t];
    }

    // ---- LN over 256 ----
    s1 = (t < 256) ? y : 0.0f;
    s2 = (t < 256) ? y * y : 0.0f;
    #pragma unroll
    for (int d = 32; d > 0; d >>= 1) {
        s1 += __shfl_xor(s1, d);
        s2 += __shfl_xor(s2, d);
    }
    if (lane == 0) { wredA[wid] = s1; wredB[wid] = s2; }
    __syncthreads();
    mu = 0.0f; m2 = 0.0f;
    #pragma unroll
    for (int i = 0; i < 16; ++i) { mu += wredA[i]; m2 += wredB[i]; }
    mu *= (1.0f / 256.0f);
    m2  = m2 * (1.0f / 256.0f) - mu * mu;
    const float rs2 = rsqrtf(m2 + 1e-5f);
    if (t < 256) h2s[t] = fmaxf((y - mu) * rs2 * g2[t] + be2[t], 0.0f);
    __syncthreads();

    // ---- GEMM3: 128 cols x 8-way K-split ----
    const int col3 = t & 127, ks3 = t >> 7;
    float o = 0.0f;
    #pragma unroll 8
    for (int k = 0; k < 32; ++k)
        o += h2s[ks3 * 32 + k] * W3[(size_t)(ks3 * 32 + k) * 128 + col3];
    red[t] = o;
    __syncthreads();
    if (t < 128) {
        float oo = 0.0f;
        #pragma unroll
        for (int s = 0; s < 8; ++s) oo += red[t + s * 128];
        out[(size_t)row * 128 + t] = oo + b3[t];
    }
}

// ---------------------------------------------------------------------------
extern "C" void kernel_launch(void* const* d_in, const int* in_sizes, int n_in,
                              void* d_out, int out_size, void* d_ws, size_t ws_size,
                              hipStream_t stream)
{
    const float* p0  = (const float*)d_in[0];
    const float* p1  = (const float*)d_in[1];
    const float* W1  = (const float*)d_in[2];
    const float* b1  = (const float*)d_in[3];
    const float* g1  = (const float*)d_in[4];
    const float* be1 = (const float*)d_in[5];
    const float* W2  = (const float*)d_in[6];
    const float* b2  = (const float*)d_in[7];
    const float* g2  = (const float*)d_in[8];
    const float* be2 = (const float*)d_in[9];
    const float* W3  = (const float*)d_in[10];
    const float* b3  = (const float*)d_in[11];
    float* out = (float*)d_out;

    // workspace: featsH 4MB | part 8MB (16 split-K slabs)
    _Float16* featsH = (_Float16*)d_ws;
    float*    part   = (float*)((char*)d_ws + (4u << 20));

    hipLaunchKernelGGL(pi_kernel,    dim3(512),      dim3(256),  0, stream, p0, p1, featsH);
    hipLaunchKernelGGL(gemm1_mfma,   dim3(4, 8, 16), dim3(256),  0, stream, featsH, W1, part);
    hipLaunchKernelGGL(tail_kernel,  dim3(256),      dim3(1024), 0, stream, part,
                       b1, g1, be1, W2, b2, g2, be2, W3, b3, out);
}